// Round 2
// baseline (2481.428 us; speedup 1.0000x reference)
//
#include <hip/hip_runtime.h>
#include <hip/hip_bf16.h>
#include <math.h>

// ---------------------------------------------------------------------------
// Generalised gated MoE U-net, B=2048, E=4, W=10, fp32 throughout.
// Round 1: conv computes ALL output channels per thread (CG group) ->
//   input fetched once (was 10x via blockIdx.y), 360 FMA per 12 loads.
//   Gate kernels float4-vectorized. final1x1 float4.
// ---------------------------------------------------------------------------

constexpr int BATCH = 2048;

// ---------------- workspace layout (in floats) ----------------
constexpr size_t PADF    = 1024;                       // 4KB guard pads
constexpr size_t F_CONV1 = (size_t)BATCH * 10 * 784;
constexpr size_t F_XPAD  = (size_t)BATCH * 784;
constexpr size_t F_P1    = (size_t)BATCH * 10 * 196;
constexpr size_t F_CONV2 = F_P1;
constexpr size_t F_P2    = (size_t)BATCH * 10 * 49;
constexpr size_t F_CONV3 = (size_t)BATCH * 20 * 49;
constexpr size_t F_UP3   = (size_t)BATCH * 20 * 196;
constexpr size_t F_M4    = F_P1;
constexpr size_t F_UP4   = F_CONV1;
constexpr size_t F_M5    = F_CONV1;

constexpr size_t O_CONV1 = PADF;
constexpr size_t O_Z2    = O_CONV1 + F_CONV1 + PADF;
constexpr size_t O_XPAD  = O_Z2;
constexpr size_t O_P1    = O_XPAD + F_XPAD + PADF;
constexpr size_t O_CONV2 = O_P1 + F_P1 + PADF;
constexpr size_t O_P2    = O_CONV2 + F_CONV2 + PADF;
constexpr size_t O_CONV3 = O_P2 + F_P2 + PADF;
constexpr size_t O_UP3   = O_CONV3 + F_CONV3 + PADF;
constexpr size_t O_M4    = O_UP3 + F_UP3 + PADF;
constexpr size_t O_UP4   = O_Z2;                        // overlays dead xpad..up3
constexpr size_t O_M5    = O_Z2 + F_UP4 + PADF;
constexpr size_t O_GRAW  = O_M5 + F_M5 + PADF;
constexpr size_t O_GATE  = O_GRAW + 5 * (size_t)BATCH * 4;
constexpr size_t O_CS    = O_GATE + 5 * (size_t)BATCH * 4;
constexpr size_t WS_FLOATS = O_CS + 5 * 64 + PADF;

__device__ __forceinline__ float softplusf(float z) {
    return fmaxf(z, 0.0f) + log1pf(expf(-fabsf(z)));
}

__device__ __forceinline__ float4 ld4(const float* p) {
    return *(const float4*)p;
}

// ---------------- gate (float4 path): C1HW/C2HW are flattened elem counts,
// both multiples of 4 ----------------
template <int C1HW, int C2HW>
__global__ __launch_bounds__(256) void gate_compute_v4(
    const float* __restrict__ x1, const float* __restrict__ x2,
    const float* __restrict__ gw, const float* __restrict__ gb,
    const float* __restrict__ nw, const float* __restrict__ nb,
    const float* __restrict__ eps,
    float* __restrict__ graw, float* __restrict__ colsum)
{
    constexpr int D  = C1HW + C2HW;
    constexpr int DV = D / 4;
    const int wave = threadIdx.x >> 6;
    const int lane = threadIdx.x & 63;
    const int b = blockIdx.x * 4 + wave;
    if (b >= BATCH) return;

    float ga0 = 0.f, ga1 = 0.f, ga2 = 0.f, ga3 = 0.f;
    float na0 = 0.f, na1 = 0.f, na2 = 0.f, na3 = 0.f;

    for (int g = lane; g < DV; g += 64) {
        const int d = g * 4;
        float4 xv;
        if constexpr (C2HW > 0) {
            xv = (d < C1HW) ? ld4(x1 + (size_t)b * C1HW + d)
                            : ld4(x2 + (size_t)b * C2HW + (d - C1HW));
        } else {
            xv = ld4(x1 + (size_t)b * C1HW + d);
        }
        const float xs[4] = {xv.x, xv.y, xv.z, xv.w};
        #pragma unroll
        for (int j = 0; j < 4; ++j) {
            const float val = xs[j];
            const float4 gv = ((const float4*)gw)[d + j];
            const float4 nv = ((const float4*)nw)[d + j];
            ga0 = fmaf(val, gv.x, ga0); ga1 = fmaf(val, gv.y, ga1);
            ga2 = fmaf(val, gv.z, ga2); ga3 = fmaf(val, gv.w, ga3);
            na0 = fmaf(val, nv.x, na0); na1 = fmaf(val, nv.y, na1);
            na2 = fmaf(val, nv.z, na2); na3 = fmaf(val, nv.w, na3);
        }
    }
    #pragma unroll
    for (int m = 32; m >= 1; m >>= 1) {
        ga0 += __shfl_xor(ga0, m, 64); ga1 += __shfl_xor(ga1, m, 64);
        ga2 += __shfl_xor(ga2, m, 64); ga3 += __shfl_xor(ga3, m, 64);
        na0 += __shfl_xor(na0, m, 64); na1 += __shfl_xor(na1, m, 64);
        na2 += __shfl_xor(na2, m, 64); na3 += __shfl_xor(na3, m, 64);
    }
    if (lane == 0) {
        float ga[4] = {ga0, ga1, ga2, ga3};
        float na[4] = {na0, na1, na2, na3};
        #pragma unroll
        for (int e = 0; e < 4; ++e) {
            float g = ga[e] + gb[e] + eps[e] * softplusf(na[e] + nb[e]);
            graw[b * 4 + e] = g;
            atomicAdd(&colsum[e], g);
        }
    }
}

// ---------------- gate (scalar path, for D not /4-friendly) ----------------
template <int C1, int C2, int HW>
__global__ __launch_bounds__(256) void gate_compute(
    const float* __restrict__ x1, const float* __restrict__ x2,
    const float* __restrict__ gw, const float* __restrict__ gb,
    const float* __restrict__ nw, const float* __restrict__ nb,
    const float* __restrict__ eps,
    float* __restrict__ graw, float* __restrict__ colsum)
{
    constexpr int D = (C1 + C2) * HW;
    const int wave = threadIdx.x >> 6;
    const int lane = threadIdx.x & 63;
    const int b = blockIdx.x * 4 + wave;
    if (b >= BATCH) return;

    float ga0 = 0.f, ga1 = 0.f, ga2 = 0.f, ga3 = 0.f;
    float na0 = 0.f, na1 = 0.f, na2 = 0.f, na3 = 0.f;

    for (int d = lane; d < D; d += 64) {
        float val;
        if constexpr (C2 > 0) {
            val = (d < C1 * HW) ? x1[(size_t)b * C1 * HW + d]
                                : x2[(size_t)b * C2 * HW + (d - C1 * HW)];
        } else {
            val = x1[(size_t)b * C1 * HW + d];
        }
        const float4 gv = ((const float4*)gw)[d];
        const float4 nv = ((const float4*)nw)[d];
        ga0 = fmaf(val, gv.x, ga0); ga1 = fmaf(val, gv.y, ga1);
        ga2 = fmaf(val, gv.z, ga2); ga3 = fmaf(val, gv.w, ga3);
        na0 = fmaf(val, nv.x, na0); na1 = fmaf(val, nv.y, na1);
        na2 = fmaf(val, nv.z, na2); na3 = fmaf(val, nv.w, na3);
    }
    #pragma unroll
    for (int m = 32; m >= 1; m >>= 1) {
        ga0 += __shfl_xor(ga0, m, 64); ga1 += __shfl_xor(ga1, m, 64);
        ga2 += __shfl_xor(ga2, m, 64); ga3 += __shfl_xor(ga3, m, 64);
        na0 += __shfl_xor(na0, m, 64); na1 += __shfl_xor(na1, m, 64);
        na2 += __shfl_xor(na2, m, 64); na3 += __shfl_xor(na3, m, 64);
    }
    if (lane == 0) {
        float ga[4] = {ga0, ga1, ga2, ga3};
        float na[4] = {na0, na1, na2, na3};
        #pragma unroll
        for (int e = 0; e < 4; ++e) {
            float g = ga[e] + gb[e] + eps[e] * softplusf(na[e] + nb[e]);
            graw[b * 4 + e] = g;
            atomicAdd(&colsum[e], g);
        }
    }
}

// ---------------- gate finalize: top-k mask (by colsum) + masked softmax ----
__global__ __launch_bounds__(256) void gate_finalize(
    const float* __restrict__ graw, const float* __restrict__ colsum,
    const int* __restrict__ kp, float* __restrict__ gate)
{
    const int b = blockIdx.x * 256 + threadIdx.x;
    if (b >= BATCH) return;
    int k = kp[0];
    k = (k < 1) ? 1 : (k > 4 ? 4 : k);

    float cs[4];
    bool sel[4] = {false, false, false, false};
    #pragma unroll
    for (int e = 0; e < 4; ++e) cs[e] = colsum[e];
    for (int it = 0; it < k; ++it) {
        int bi = 0; float bv = -INFINITY;
        #pragma unroll
        for (int e = 0; e < 4; ++e)
            if (!sel[e] && cs[e] > bv) { bv = cs[e]; bi = e; }
        sel[bi] = true;
    }
    float g[4];
    #pragma unroll
    for (int e = 0; e < 4; ++e) {
        float v = graw[b * 4 + e];
        g[e] = sel[e] ? v : 0.0f;   // zero BEFORE softmax (as in reference)
    }
    float m = fmaxf(fmaxf(g[0], g[1]), fmaxf(g[2], g[3]));
    float e0 = expf(g[0] - m), e1 = expf(g[1] - m);
    float e2 = expf(g[2] - m), e3 = expf(g[3] - m);
    float inv = 1.0f / (e0 + e1 + e2 + e3);
    gate[b * 4 + 0] = e0 * inv; gate[b * 4 + 1] = e1 * inv;
    gate[b * 4 + 2] = e2 * inv; gate[b * 4 + 3] = e3 * inv;
}

// ---------------- MoE conv 3x3 SAME + relu + gated expert sum --------------
// Thread = (b, w, row pair). Computes CG output channels x 4 experts.
// Weights wave-uniform (e, c, ci uniform) -> scalar loads.
template <int CIN1, int CIN2, int CG, int COUT, int H, int W>
__global__ __launch_bounds__(256) void moe_conv(
    const float* __restrict__ x1, const float* __restrict__ x2,
    const float* __restrict__ cw, const float* __restrict__ cb,
    const float* __restrict__ gate, float* __restrict__ out)
{
    constexpr int CIN = CIN1 + CIN2;
    constexpr int H2 = (H + 1) / 2;
    const int c0 = blockIdx.y * CG;
    const int t = blockIdx.x * 256 + threadIdx.x;
    constexpr int TOTAL = BATCH * H2 * W;
    if (t >= TOTAL) return;
    const int b  = t / (H2 * W);
    const int r  = t - b * (H2 * W);
    const int h2 = r / W;
    const int w  = r - h2 * W;
    const int h0 = 2 * h2;

    float acc0[CG][4], acc1[CG][4];
    #pragma unroll
    for (int j = 0; j < CG; ++j) {
        #pragma unroll
        for (int e = 0; e < 4; ++e) {
            float bv = cb[e * COUT + c0 + j];
            acc0[j][e] = bv; acc1[j][e] = bv;
        }
    }

    float msk[4][3];
    int   base[4];
    #pragma unroll
    for (int rr = 0; rr < 4; ++rr) {
        const int y = h0 - 1 + rr;
        const float my = (y >= 0 && y < H) ? 1.0f : 0.0f;
        base[rr] = y * W + (w - 1);
        #pragma unroll
        for (int dc = 0; dc < 3; ++dc) {
            const int xx = w - 1 + dc;
            msk[rr][dc] = ((xx >= 0 && xx < W) ? 1.0f : 0.0f) * my;
        }
    }

    const float* xb1 = x1 + (size_t)b * CIN1 * (H * W);
    const float* xb2 = (CIN2 > 0) ? (x2 + (size_t)b * CIN2 * (H * W)) : nullptr;

    for (int ci = 0; ci < CIN; ++ci) {
        const float* xp;
        if constexpr (CIN2 > 0) {
            xp = (ci < CIN1) ? (xb1 + ci * (H * W)) : (xb2 + (ci - CIN1) * (H * W));
        } else {
            xp = xb1 + ci * (H * W);
        }
        float v[4][3];
        #pragma unroll
        for (int rr = 0; rr < 4; ++rr) {
            #pragma unroll
            for (int dc = 0; dc < 3; ++dc) {
                v[rr][dc] = xp[base[rr] + dc] * msk[rr][dc];
            }
        }
        #pragma unroll
        for (int j = 0; j < CG; ++j) {
            #pragma unroll
            for (int e = 0; e < 4; ++e) {
                const float* wp = cw + (((size_t)(e * COUT + c0 + j) * CIN + ci) * 9);
                #pragma unroll
                for (int kh = 0; kh < 3; ++kh) {
                    #pragma unroll
                    for (int kw = 0; kw < 3; ++kw) {
                        const float wv = wp[kh * 3 + kw];   // uniform -> s_load
                        acc0[j][e] = fmaf(v[kh][kw],     wv, acc0[j][e]);
                        acc1[j][e] = fmaf(v[kh + 1][kw], wv, acc1[j][e]);
                    }
                }
            }
        }
    }

    const float* gp = gate + b * 4;
    const float g0 = gp[0], g1 = gp[1], g2 = gp[2], g3 = gp[3];
    #pragma unroll
    for (int j = 0; j < CG; ++j) {
        float r0 = g0 * fmaxf(acc0[j][0], 0.f) + g1 * fmaxf(acc0[j][1], 0.f)
                 + g2 * fmaxf(acc0[j][2], 0.f) + g3 * fmaxf(acc0[j][3], 0.f);
        float r1 = g0 * fmaxf(acc1[j][0], 0.f) + g1 * fmaxf(acc1[j][1], 0.f)
                 + g2 * fmaxf(acc1[j][2], 0.f) + g3 * fmaxf(acc1[j][3], 0.f);
        float* op = out + ((size_t)b * COUT + c0 + j) * (H * W) + h0 * W + w;
        op[0] = r0;
        if (h0 + 1 < H) op[W] = r1;
    }
}

// ---------------- 2x2 maxpool stride 2 ----------------
template <int N>
__global__ __launch_bounds__(256) void maxpool2(
    const float* __restrict__ in, float* __restrict__ out, int BC)
{
    constexpr int N2 = N / 2;
    const int idx = blockIdx.x * 256 + threadIdx.x;
    const int total = BC * N2 * N2;
    if (idx >= total) return;
    const int j = idx % N2;
    int tmp = idx / N2;
    const int i = tmp % N2;
    const int bc = tmp / N2;
    const float* p = in + (size_t)bc * N * N + (2 * i) * N + 2 * j;
    out[idx] = fmaxf(fmaxf(p[0], p[1]), fmaxf(p[N], p[N + 1]));
}

// ---------------- bilinear x2 upsample, align_corners=True ----------------
template <int N>
__global__ __launch_bounds__(256) void upsample2(
    const float* __restrict__ in, float* __restrict__ out, int BC)
{
    constexpr int M = 2 * N;
    const int idx = blockIdx.x * 256 + threadIdx.x;
    const int total = BC * M * M;
    if (idx >= total) return;
    const int x = idx % M;
    int tmp = idx / M;
    const int y = tmp % M;
    const int bc = tmp / M;
    const float scale = (float)((double)(N - 1) / (double)(M - 1));
    const float cy = (float)y * scale;
    const float cx = (float)x * scale;
    const int iy0 = (int)floorf(cy);
    const int ix0 = (int)floorf(cx);
    const int iy1 = min(iy0 + 1, N - 1);
    const int ix1 = min(ix0 + 1, N - 1);
    const float wy = cy - (float)iy0;
    const float wx = cx - (float)ix0;
    const float* p = in + (size_t)bc * N * N;
    const float v00 = p[iy0 * N + ix0], v01 = p[iy0 * N + ix1];
    const float v10 = p[iy1 * N + ix0], v11 = p[iy1 * N + ix1];
    const float a0 = v00 * (1.0f - wy) + v10 * wy;
    const float a1 = v01 * (1.0f - wy) + v11 * wy;
    out[idx] = a0 * (1.0f - wx) + a1 * wx;
}

// ---------------- final 1x1 conv (float4) ----------------
__global__ __launch_bounds__(256) void final1x1(
    const float* __restrict__ h, const float* __restrict__ wl,
    const float* __restrict__ bl, float* __restrict__ out)
{
    const int idx = blockIdx.x * 256 + threadIdx.x;
    const int total = BATCH * 196;          // 784/4 per image
    if (idx >= total) return;
    const int s4 = idx % 196;
    const int b = idx / 196;
    const float b0 = bl[0];
    float4 acc = {b0, b0, b0, b0};
    #pragma unroll
    for (int c = 0; c < 10; ++c) {
        const float wv = wl[c];
        const float4 v = ld4(h + ((size_t)b * 10 + c) * 784 + s4 * 4);
        acc.x = fmaf(v.x, wv, acc.x); acc.y = fmaf(v.y, wv, acc.y);
        acc.z = fmaf(v.z, wv, acc.z); acc.w = fmaf(v.w, wv, acc.w);
    }
    ((float4*)out)[idx] = acc;
}

// ---------------------------------------------------------------------------
extern "C" void kernel_launch(void* const* d_in, const int* in_sizes, int n_in,
                              void* d_out, int out_size, void* d_ws, size_t ws_size,
                              hipStream_t stream)
{
    const float* x = (const float*)d_in[0];
    const float* cw[5]; const float* cb[5]; const float* gw[5]; const float* gb[5];
    const float* nw[5]; const float* nb[5]; const float* epsv[5];
    for (int l = 0; l < 5; ++l) {
        cw[l]   = (const float*)d_in[1 + 7 * l + 0];
        cb[l]   = (const float*)d_in[1 + 7 * l + 1];
        gw[l]   = (const float*)d_in[1 + 7 * l + 2];
        gb[l]   = (const float*)d_in[1 + 7 * l + 3];
        nw[l]   = (const float*)d_in[1 + 7 * l + 4];
        nb[l]   = (const float*)d_in[1 + 7 * l + 5];
        epsv[l] = (const float*)d_in[1 + 7 * l + 6];
    }
    const float* wlast = (const float*)d_in[36];
    const float* blast = (const float*)d_in[37];
    const int*   kp    = (const int*)d_in[38];
    float* out = (float*)d_out;
    float* ws  = (float*)d_ws;

    float* conv1 = ws + O_CONV1;
    float* xpad  = ws + O_XPAD;
    float* p1    = ws + O_P1;
    float* conv2 = ws + O_CONV2;
    float* p2    = ws + O_P2;
    float* conv3 = ws + O_CONV3;
    float* up3   = ws + O_UP3;
    float* m4    = ws + O_M4;
    float* up4   = ws + O_UP4;
    float* m5    = ws + O_M5;
    float* graw[5]; float* gatep[5]; float* cs[5];
    for (int l = 0; l < 5; ++l) {
        graw[l]  = ws + O_GRAW + (size_t)l * BATCH * 4;
        gatep[l] = ws + O_GATE + (size_t)l * BATCH * 4;
        cs[l]    = ws + O_CS + (size_t)l * 64;
    }

    hipMemsetAsync(ws + O_CS, 0, 5 * 64 * sizeof(float), stream);
    hipMemcpyAsync(xpad, x, (size_t)BATCH * 784 * sizeof(float),
                   hipMemcpyDeviceToDevice, stream);

    const int GB = BATCH / 4;
    #define CDIV(a) (((a) + 255) / 256)

    // ---- layer 1: x [B,1,28,28] -> conv1 [B,10,28,28]
    gate_compute_v4<784, 0><<<GB, 256, 0, stream>>>(
        x, nullptr, gw[0], gb[0], nw[0], nb[0], epsv[0], graw[0], cs[0]);
    gate_finalize<<<CDIV(BATCH), 256, 0, stream>>>(graw[0], cs[0], kp, gatep[0]);
    moe_conv<1, 0, 10, 10, 28, 28><<<dim3(CDIV(BATCH * 14 * 28), 1), 256, 0, stream>>>(
        xpad, nullptr, cw[0], cb[0], gatep[0], conv1);
    maxpool2<28><<<CDIV(BATCH * 10 * 196), 256, 0, stream>>>(conv1, p1, BATCH * 10);

    // ---- layer 2: p1 [B,10,14,14] -> conv2 [B,10,14,14]
    gate_compute_v4<1960, 0><<<GB, 256, 0, stream>>>(
        p1, nullptr, gw[1], gb[1], nw[1], nb[1], epsv[1], graw[1], cs[1]);
    gate_finalize<<<CDIV(BATCH), 256, 0, stream>>>(graw[1], cs[1], kp, gatep[1]);
    moe_conv<10, 0, 10, 10, 14, 14><<<dim3(CDIV(BATCH * 7 * 14), 1), 256, 0, stream>>>(
        p1, nullptr, cw[1], cb[1], gatep[1], conv2);
    maxpool2<14><<<CDIV(BATCH * 10 * 49), 256, 0, stream>>>(conv2, p2, BATCH * 10);

    // ---- layer 3: p2 [B,10,7,7] -> conv3 [B,20,7,7]  (D=490, scalar gate)
    gate_compute<10, 0, 49><<<GB, 256, 0, stream>>>(
        p2, nullptr, gw[2], gb[2], nw[2], nb[2], epsv[2], graw[2], cs[2]);
    gate_finalize<<<CDIV(BATCH), 256, 0, stream>>>(graw[2], cs[2], kp, gatep[2]);
    moe_conv<10, 0, 10, 20, 7, 7><<<dim3(CDIV(BATCH * 4 * 7), 2), 256, 0, stream>>>(
        p2, nullptr, cw[2], cb[2], gatep[2], conv3);
    upsample2<7><<<CDIV(BATCH * 20 * 196), 256, 0, stream>>>(conv3, up3, BATCH * 20);

    // ---- layer 4: virtual concat [up3(20ch) | conv2(10ch)] -> m4
    gate_compute_v4<3920, 1960><<<GB, 256, 0, stream>>>(
        up3, conv2, gw[3], gb[3], nw[3], nb[3], epsv[3], graw[3], cs[3]);
    gate_finalize<<<CDIV(BATCH), 256, 0, stream>>>(graw[3], cs[3], kp, gatep[3]);
    moe_conv<20, 10, 10, 10, 14, 14><<<dim3(CDIV(BATCH * 7 * 14), 1), 256, 0, stream>>>(
        up3, conv2, cw[3], cb[3], gatep[3], m4);
    upsample2<14><<<CDIV(BATCH * 10 * 784), 256, 0, stream>>>(m4, up4, BATCH * 10);

    // ---- layer 5: virtual concat [up4(10ch) | conv1(10ch)] -> m5
    gate_compute_v4<7840, 7840><<<GB, 256, 0, stream>>>(
        up4, conv1, gw[4], gb[4], nw[4], nb[4], epsv[4], graw[4], cs[4]);
    gate_finalize<<<CDIV(BATCH), 256, 0, stream>>>(graw[4], cs[4], kp, gatep[4]);
    moe_conv<10, 10, 10, 10, 28, 28><<<dim3(CDIV(BATCH * 14 * 28), 1), 256, 0, stream>>>(
        up4, conv1, cw[4], cb[4], gatep[4], m5);

    // ---- final 1x1
    final1x1<<<CDIV(BATCH * 196), 256, 0, stream>>>(m5, wlast, blast, out);
    #undef CDIV
}

// Round 3
// 2094.196 us; speedup vs baseline: 1.1849x; 1.1849x over previous
//
#include <hip/hip_runtime.h>
#include <hip/hip_bf16.h>
#include <math.h>

// ---------------------------------------------------------------------------
// Generalised gated MoE U-net, B=2048, E=4, W=10, fp32 throughout.
// Round 3: conv thread = 7-row column x (CG=2 cout) x 4 experts.
//   acc[7][2][4]=56 regs (no spill), weights staged in LDS once per block,
//   broadcast ds_read_b128 in inner loop (no s_load streaming).
//   co-group = minor grid dim -> input re-reads hit L2/L3.
// ---------------------------------------------------------------------------

constexpr int BATCH = 2048;

// ---------------- workspace layout (in floats) ----------------
constexpr size_t PADF    = 1024;                       // 4KB guard pads
constexpr size_t F_CONV1 = (size_t)BATCH * 10 * 784;
constexpr size_t F_XPAD  = (size_t)BATCH * 784;
constexpr size_t F_P1    = (size_t)BATCH * 10 * 196;
constexpr size_t F_CONV2 = F_P1;
constexpr size_t F_P2    = (size_t)BATCH * 10 * 49;
constexpr size_t F_CONV3 = (size_t)BATCH * 20 * 49;
constexpr size_t F_UP3   = (size_t)BATCH * 20 * 196;
constexpr size_t F_M4    = F_P1;
constexpr size_t F_UP4   = F_CONV1;
constexpr size_t F_M5    = F_CONV1;

constexpr size_t O_CONV1 = PADF;
constexpr size_t O_Z2    = O_CONV1 + F_CONV1 + PADF;
constexpr size_t O_XPAD  = O_Z2;
constexpr size_t O_P1    = O_XPAD + F_XPAD + PADF;
constexpr size_t O_CONV2 = O_P1 + F_P1 + PADF;
constexpr size_t O_P2    = O_CONV2 + F_CONV2 + PADF;
constexpr size_t O_CONV3 = O_P2 + F_P2 + PADF;
constexpr size_t O_UP3   = O_CONV3 + F_CONV3 + PADF;
constexpr size_t O_M4    = O_UP3 + F_UP3 + PADF;
constexpr size_t O_UP4   = O_Z2;                        // overlays dead xpad..up3
constexpr size_t O_M5    = O_Z2 + F_UP4 + PADF;
constexpr size_t O_GRAW  = O_M5 + F_M5 + PADF;
constexpr size_t O_GATE  = O_GRAW + 5 * (size_t)BATCH * 4;
constexpr size_t O_CS    = O_GATE + 5 * (size_t)BATCH * 4;
constexpr size_t WS_FLOATS = O_CS + 5 * 64 + PADF;

__device__ __forceinline__ float softplusf(float z) {
    return fmaxf(z, 0.0f) + log1pf(expf(-fabsf(z)));
}

__device__ __forceinline__ float4 ld4(const float* p) {
    return *(const float4*)p;
}

// ---------------- gate (float4 path) ----------------
template <int C1HW, int C2HW>
__global__ __launch_bounds__(256) void gate_compute_v4(
    const float* __restrict__ x1, const float* __restrict__ x2,
    const float* __restrict__ gw, const float* __restrict__ gb,
    const float* __restrict__ nw, const float* __restrict__ nb,
    const float* __restrict__ eps,
    float* __restrict__ graw, float* __restrict__ colsum)
{
    constexpr int D  = C1HW + C2HW;
    constexpr int DV = D / 4;
    const int wave = threadIdx.x >> 6;
    const int lane = threadIdx.x & 63;
    const int b = blockIdx.x * 4 + wave;
    if (b >= BATCH) return;

    float ga0 = 0.f, ga1 = 0.f, ga2 = 0.f, ga3 = 0.f;
    float na0 = 0.f, na1 = 0.f, na2 = 0.f, na3 = 0.f;

    for (int g = lane; g < DV; g += 64) {
        const int d = g * 4;
        float4 xv;
        if constexpr (C2HW > 0) {
            xv = (d < C1HW) ? ld4(x1 + (size_t)b * C1HW + d)
                            : ld4(x2 + (size_t)b * C2HW + (d - C1HW));
        } else {
            xv = ld4(x1 + (size_t)b * C1HW + d);
        }
        const float xs[4] = {xv.x, xv.y, xv.z, xv.w};
        #pragma unroll
        for (int j = 0; j < 4; ++j) {
            const float val = xs[j];
            const float4 gv = ((const float4*)gw)[d + j];
            const float4 nv = ((const float4*)nw)[d + j];
            ga0 = fmaf(val, gv.x, ga0); ga1 = fmaf(val, gv.y, ga1);
            ga2 = fmaf(val, gv.z, ga2); ga3 = fmaf(val, gv.w, ga3);
            na0 = fmaf(val, nv.x, na0); na1 = fmaf(val, nv.y, na1);
            na2 = fmaf(val, nv.z, na2); na3 = fmaf(val, nv.w, na3);
        }
    }
    #pragma unroll
    for (int m = 32; m >= 1; m >>= 1) {
        ga0 += __shfl_xor(ga0, m, 64); ga1 += __shfl_xor(ga1, m, 64);
        ga2 += __shfl_xor(ga2, m, 64); ga3 += __shfl_xor(ga3, m, 64);
        na0 += __shfl_xor(na0, m, 64); na1 += __shfl_xor(na1, m, 64);
        na2 += __shfl_xor(na2, m, 64); na3 += __shfl_xor(na3, m, 64);
    }
    if (lane == 0) {
        float ga[4] = {ga0, ga1, ga2, ga3};
        float na[4] = {na0, na1, na2, na3};
        #pragma unroll
        for (int e = 0; e < 4; ++e) {
            float g = ga[e] + gb[e] + eps[e] * softplusf(na[e] + nb[e]);
            graw[b * 4 + e] = g;
            atomicAdd(&colsum[e], g);
        }
    }
}

// ---------------- gate (scalar path, D=490) ----------------
template <int C1, int C2, int HW>
__global__ __launch_bounds__(256) void gate_compute(
    const float* __restrict__ x1, const float* __restrict__ x2,
    const float* __restrict__ gw, const float* __restrict__ gb,
    const float* __restrict__ nw, const float* __restrict__ nb,
    const float* __restrict__ eps,
    float* __restrict__ graw, float* __restrict__ colsum)
{
    constexpr int D = (C1 + C2) * HW;
    const int wave = threadIdx.x >> 6;
    const int lane = threadIdx.x & 63;
    const int b = blockIdx.x * 4 + wave;
    if (b >= BATCH) return;

    float ga0 = 0.f, ga1 = 0.f, ga2 = 0.f, ga3 = 0.f;
    float na0 = 0.f, na1 = 0.f, na2 = 0.f, na3 = 0.f;

    for (int d = lane; d < D; d += 64) {
        float val;
        if constexpr (C2 > 0) {
            val = (d < C1 * HW) ? x1[(size_t)b * C1 * HW + d]
                                : x2[(size_t)b * C2 * HW + (d - C1 * HW)];
        } else {
            val = x1[(size_t)b * C1 * HW + d];
        }
        const float4 gv = ((const float4*)gw)[d];
        const float4 nv = ((const float4*)nw)[d];
        ga0 = fmaf(val, gv.x, ga0); ga1 = fmaf(val, gv.y, ga1);
        ga2 = fmaf(val, gv.z, ga2); ga3 = fmaf(val, gv.w, ga3);
        na0 = fmaf(val, nv.x, na0); na1 = fmaf(val, nv.y, na1);
        na2 = fmaf(val, nv.z, na2); na3 = fmaf(val, nv.w, na3);
    }
    #pragma unroll
    for (int m = 32; m >= 1; m >>= 1) {
        ga0 += __shfl_xor(ga0, m, 64); ga1 += __shfl_xor(ga1, m, 64);
        ga2 += __shfl_xor(ga2, m, 64); ga3 += __shfl_xor(ga3, m, 64);
        na0 += __shfl_xor(na0, m, 64); na1 += __shfl_xor(na1, m, 64);
        na2 += __shfl_xor(na2, m, 64); na3 += __shfl_xor(na3, m, 64);
    }
    if (lane == 0) {
        float ga[4] = {ga0, ga1, ga2, ga3};
        float na[4] = {na0, na1, na2, na3};
        #pragma unroll
        for (int e = 0; e < 4; ++e) {
            float g = ga[e] + gb[e] + eps[e] * softplusf(na[e] + nb[e]);
            graw[b * 4 + e] = g;
            atomicAdd(&colsum[e], g);
        }
    }
}

// ---------------- gate finalize ----------------
__global__ __launch_bounds__(256) void gate_finalize(
    const float* __restrict__ graw, const float* __restrict__ colsum,
    const int* __restrict__ kp, float* __restrict__ gate)
{
    const int b = blockIdx.x * 256 + threadIdx.x;
    if (b >= BATCH) return;
    int k = kp[0];
    k = (k < 1) ? 1 : (k > 4 ? 4 : k);

    float cs[4];
    bool sel[4] = {false, false, false, false};
    #pragma unroll
    for (int e = 0; e < 4; ++e) cs[e] = colsum[e];
    for (int it = 0; it < k; ++it) {
        int bi = 0; float bv = -INFINITY;
        #pragma unroll
        for (int e = 0; e < 4; ++e)
            if (!sel[e] && cs[e] > bv) { bv = cs[e]; bi = e; }
        sel[bi] = true;
    }
    float g[4];
    #pragma unroll
    for (int e = 0; e < 4; ++e) {
        float v = graw[b * 4 + e];
        g[e] = sel[e] ? v : 0.0f;   // zero BEFORE softmax (as in reference)
    }
    float m = fmaxf(fmaxf(g[0], g[1]), fmaxf(g[2], g[3]));
    float e0 = expf(g[0] - m), e1 = expf(g[1] - m);
    float e2 = expf(g[2] - m), e3 = expf(g[3] - m);
    float inv = 1.0f / (e0 + e1 + e2 + e3);
    gate[b * 4 + 0] = e0 * inv; gate[b * 4 + 1] = e1 * inv;
    gate[b * 4 + 2] = e2 * inv; gate[b * 4 + 3] = e3 * inv;
}

// ---------------- MoE conv 3x3 SAME + relu + gated expert sum --------------
// Thread = (b, w, 7-row column) x CG=2 output channels x 4 experts.
// Block stages its (CG x 4 x CIN x 9) weight slice into LDS; inner loop
// reads them as wave-uniform broadcasts (b128+b128+b32 per 63 FMA).
template <int CIN1, int CIN2, int COUT, int H, int W>
__global__ __launch_bounds__(256) void moe_conv7(
    const float* __restrict__ x1, const float* __restrict__ x2,
    const float* __restrict__ cw, const float* __restrict__ cb,
    const float* __restrict__ gate, float* __restrict__ out)
{
    constexpr int CIN = CIN1 + CIN2;
    constexpr int CG  = 2;
    constexpr int NCG = COUT / CG;
    constexpr int HG  = (H + 6) / 7;
    constexpr int TOTAL = BATCH * HG * W;

    __shared__ __align__(16) float wlds[CIN * CG * 4 * 12];

    const int cg = blockIdx.x % NCG;
    const int pb = blockIdx.x / NCG;
    const int c0 = cg * CG;

    // cooperative weight staging: [ci][j][e][12] (pad 9->12 for b128 align)
    for (int idx = threadIdx.x; idx < CIN * 72; idx += 256) {
        const int ci  = idx / 72;
        const int rem = idx % 72;
        const int j   = rem / 36;
        const int e   = (rem % 36) / 9;
        const int kk  = rem % 9;
        wlds[((ci * CG + j) * 4 + e) * 12 + kk] =
            cw[((size_t)(e * COUT + c0 + j) * CIN + ci) * 9 + kk];
    }
    __syncthreads();

    const int t = pb * 256 + threadIdx.x;
    if (t >= TOTAL) return;
    const int b  = t / (HG * W);
    const int r  = t - b * (HG * W);
    const int hg = r / W;
    const int w  = r - hg * W;
    const int h0 = hg * 7;

    float mrow[9];
    float mcol[3];
    int   base[9];
    #pragma unroll
    for (int rr = 0; rr < 9; ++rr) {
        const int y = h0 - 1 + rr;
        mrow[rr] = (y >= 0 && y < H) ? 1.0f : 0.0f;
        base[rr] = y * W + (w - 1);
    }
    #pragma unroll
    for (int dc = 0; dc < 3; ++dc) {
        const int xx = w - 1 + dc;
        mcol[dc] = (xx >= 0 && xx < W) ? 1.0f : 0.0f;
    }

    float acc[7][CG][4];
    #pragma unroll
    for (int j = 0; j < CG; ++j) {
        #pragma unroll
        for (int e = 0; e < 4; ++e) {
            const float bv = cb[e * COUT + c0 + j];
            #pragma unroll
            for (int rr = 0; rr < 7; ++rr) acc[rr][j][e] = bv;
        }
    }

    const float* xb1 = x1 + (size_t)b * CIN1 * (H * W);
    const float* xb2 = (CIN2 > 0) ? (x2 + (size_t)b * CIN2 * (H * W)) : nullptr;

    for (int ci = 0; ci < CIN; ++ci) {
        const float* xp;
        if constexpr (CIN2 > 0) {
            xp = (ci < CIN1) ? (xb1 + ci * (H * W)) : (xb2 + (ci - CIN1) * (H * W));
        } else {
            xp = xb1 + ci * (H * W);
        }
        float v[9][3];
        #pragma unroll
        for (int rr = 0; rr < 9; ++rr) {
            #pragma unroll
            for (int dc = 0; dc < 3; ++dc) {
                v[rr][dc] = (xp[base[rr] + dc] * mcol[dc]) * mrow[rr];
            }
        }
        #pragma unroll
        for (int j = 0; j < CG; ++j) {
            #pragma unroll
            for (int e = 0; e < 4; ++e) {
                const float* wp = &wlds[((ci * CG + j) * 4 + e) * 12];
                const float4 wa = *(const float4*)wp;       // w00 w01 w02 w10
                const float4 wb = *(const float4*)(wp + 4); // w11 w12 w20 w21
                const float  w8 = wp[8];                    // w22
                #pragma unroll
                for (int rr = 0; rr < 7; ++rr) {
                    float a = acc[rr][j][e];
                    a = fmaf(v[rr    ][0], wa.x, a);
                    a = fmaf(v[rr    ][1], wa.y, a);
                    a = fmaf(v[rr    ][2], wa.z, a);
                    a = fmaf(v[rr + 1][0], wa.w, a);
                    a = fmaf(v[rr + 1][1], wb.x, a);
                    a = fmaf(v[rr + 1][2], wb.y, a);
                    a = fmaf(v[rr + 2][0], wb.z, a);
                    a = fmaf(v[rr + 2][1], wb.w, a);
                    a = fmaf(v[rr + 2][2], w8,   a);
                    acc[rr][j][e] = a;
                }
            }
        }
    }

    const float4 gv = ld4(gate + b * 4);
    #pragma unroll
    for (int j = 0; j < CG; ++j) {
        float* op = out + ((size_t)b * COUT + c0 + j) * (H * W) + h0 * W + w;
        #pragma unroll
        for (int rr = 0; rr < 7; ++rr) {
            const float s = gv.x * fmaxf(acc[rr][j][0], 0.f)
                          + gv.y * fmaxf(acc[rr][j][1], 0.f)
                          + gv.z * fmaxf(acc[rr][j][2], 0.f)
                          + gv.w * fmaxf(acc[rr][j][3], 0.f);
            op[rr * W] = s;
        }
    }
}

// ---------------- 2x2 maxpool stride 2 ----------------
template <int N>
__global__ __launch_bounds__(256) void maxpool2(
    const float* __restrict__ in, float* __restrict__ out, int BC)
{
    constexpr int N2 = N / 2;
    const int idx = blockIdx.x * 256 + threadIdx.x;
    const int total = BC * N2 * N2;
    if (idx >= total) return;
    const int j = idx % N2;
    int tmp = idx / N2;
    const int i = tmp % N2;
    const int bc = tmp / N2;
    const float* p = in + (size_t)bc * N * N + (2 * i) * N + 2 * j;
    out[idx] = fmaxf(fmaxf(p[0], p[1]), fmaxf(p[N], p[N + 1]));
}

// ---------------- bilinear x2 upsample, align_corners=True ----------------
template <int N>
__global__ __launch_bounds__(256) void upsample2(
    const float* __restrict__ in, float* __restrict__ out, int BC)
{
    constexpr int M = 2 * N;
    const int idx = blockIdx.x * 256 + threadIdx.x;
    const int total = BC * M * M;
    if (idx >= total) return;
    const int x = idx % M;
    int tmp = idx / M;
    const int y = tmp % M;
    const int bc = tmp / M;
    const float scale = (float)((double)(N - 1) / (double)(M - 1));
    const float cy = (float)y * scale;
    const float cx = (float)x * scale;
    const int iy0 = (int)floorf(cy);
    const int ix0 = (int)floorf(cx);
    const int iy1 = min(iy0 + 1, N - 1);
    const int ix1 = min(ix0 + 1, N - 1);
    const float wy = cy - (float)iy0;
    const float wx = cx - (float)ix0;
    const float* p = in + (size_t)bc * N * N;
    const float v00 = p[iy0 * N + ix0], v01 = p[iy0 * N + ix1];
    const float v10 = p[iy1 * N + ix0], v11 = p[iy1 * N + ix1];
    const float a0 = v00 * (1.0f - wy) + v10 * wy;
    const float a1 = v01 * (1.0f - wy) + v11 * wy;
    out[idx] = a0 * (1.0f - wx) + a1 * wx;
}

// ---------------- final 1x1 conv (float4) ----------------
__global__ __launch_bounds__(256) void final1x1(
    const float* __restrict__ h, const float* __restrict__ wl,
    const float* __restrict__ bl, float* __restrict__ out)
{
    const int idx = blockIdx.x * 256 + threadIdx.x;
    const int total = BATCH * 196;
    if (idx >= total) return;
    const int s4 = idx % 196;
    const int b = idx / 196;
    const float b0 = bl[0];
    float4 acc = {b0, b0, b0, b0};
    #pragma unroll
    for (int c = 0; c < 10; ++c) {
        const float wv = wl[c];
        const float4 v = ld4(h + ((size_t)b * 10 + c) * 784 + s4 * 4);
        acc.x = fmaf(v.x, wv, acc.x); acc.y = fmaf(v.y, wv, acc.y);
        acc.z = fmaf(v.z, wv, acc.z); acc.w = fmaf(v.w, wv, acc.w);
    }
    ((float4*)out)[idx] = acc;
}

// ---------------------------------------------------------------------------
extern "C" void kernel_launch(void* const* d_in, const int* in_sizes, int n_in,
                              void* d_out, int out_size, void* d_ws, size_t ws_size,
                              hipStream_t stream)
{
    const float* x = (const float*)d_in[0];
    const float* cw[5]; const float* cb[5]; const float* gw[5]; const float* gb[5];
    const float* nw[5]; const float* nb[5]; const float* epsv[5];
    for (int l = 0; l < 5; ++l) {
        cw[l]   = (const float*)d_in[1 + 7 * l + 0];
        cb[l]   = (const float*)d_in[1 + 7 * l + 1];
        gw[l]   = (const float*)d_in[1 + 7 * l + 2];
        gb[l]   = (const float*)d_in[1 + 7 * l + 3];
        nw[l]   = (const float*)d_in[1 + 7 * l + 4];
        nb[l]   = (const float*)d_in[1 + 7 * l + 5];
        epsv[l] = (const float*)d_in[1 + 7 * l + 6];
    }
    const float* wlast = (const float*)d_in[36];
    const float* blast = (const float*)d_in[37];
    const int*   kp    = (const int*)d_in[38];
    float* out = (float*)d_out;
    float* ws  = (float*)d_ws;

    float* conv1 = ws + O_CONV1;
    float* xpad  = ws + O_XPAD;
    float* p1    = ws + O_P1;
    float* conv2 = ws + O_CONV2;
    float* p2    = ws + O_P2;
    float* conv3 = ws + O_CONV3;
    float* up3   = ws + O_UP3;
    float* m4    = ws + O_M4;
    float* up4   = ws + O_UP4;
    float* m5    = ws + O_M5;
    float* graw[5]; float* gatep[5]; float* cs[5];
    for (int l = 0; l < 5; ++l) {
        graw[l]  = ws + O_GRAW + (size_t)l * BATCH * 4;
        gatep[l] = ws + O_GATE + (size_t)l * BATCH * 4;
        cs[l]    = ws + O_CS + (size_t)l * 64;
    }

    hipMemsetAsync(ws + O_CS, 0, 5 * 64 * sizeof(float), stream);
    hipMemcpyAsync(xpad, x, (size_t)BATCH * 784 * sizeof(float),
                   hipMemcpyDeviceToDevice, stream);

    const int GB = BATCH / 4;
    #define CDIV(a) (((a) + 255) / 256)

    // conv grids: CDIV(BATCH*HG*W) * NCG
    const int g1 = CDIV(BATCH * 4 * 28) * 5;   // L1: H=28, COUT=10
    const int g2 = CDIV(BATCH * 2 * 14) * 5;   // L2: H=14
    const int g3 = CDIV(BATCH * 1 * 7)  * 10;  // L3: H=7,  COUT=20
    const int g4 = CDIV(BATCH * 2 * 14) * 5;   // L4
    const int g5 = CDIV(BATCH * 4 * 28) * 5;   // L5

    // ---- layer 1: x [B,1,28,28] -> conv1 [B,10,28,28]
    gate_compute_v4<784, 0><<<GB, 256, 0, stream>>>(
        x, nullptr, gw[0], gb[0], nw[0], nb[0], epsv[0], graw[0], cs[0]);
    gate_finalize<<<CDIV(BATCH), 256, 0, stream>>>(graw[0], cs[0], kp, gatep[0]);
    moe_conv7<1, 0, 10, 28, 28><<<g1, 256, 0, stream>>>(
        xpad, nullptr, cw[0], cb[0], gatep[0], conv1);
    maxpool2<28><<<CDIV(BATCH * 10 * 196), 256, 0, stream>>>(conv1, p1, BATCH * 10);

    // ---- layer 2: p1 [B,10,14,14] -> conv2 [B,10,14,14]
    gate_compute_v4<1960, 0><<<GB, 256, 0, stream>>>(
        p1, nullptr, gw[1], gb[1], nw[1], nb[1], epsv[1], graw[1], cs[1]);
    gate_finalize<<<CDIV(BATCH), 256, 0, stream>>>(graw[1], cs[1], kp, gatep[1]);
    moe_conv7<10, 0, 10, 14, 14><<<g2, 256, 0, stream>>>(
        p1, nullptr, cw[1], cb[1], gatep[1], conv2);
    maxpool2<14><<<CDIV(BATCH * 10 * 49), 256, 0, stream>>>(conv2, p2, BATCH * 10);

    // ---- layer 3: p2 [B,10,7,7] -> conv3 [B,20,7,7]  (D=490, scalar gate)
    gate_compute<10, 0, 49><<<GB, 256, 0, stream>>>(
        p2, nullptr, gw[2], gb[2], nw[2], nb[2], epsv[2], graw[2], cs[2]);
    gate_finalize<<<CDIV(BATCH), 256, 0, stream>>>(graw[2], cs[2], kp, gatep[2]);
    moe_conv7<10, 0, 20, 7, 7><<<g3, 256, 0, stream>>>(
        p2, nullptr, cw[2], cb[2], gatep[2], conv3);
    upsample2<7><<<CDIV(BATCH * 20 * 196), 256, 0, stream>>>(conv3, up3, BATCH * 20);

    // ---- layer 4: virtual concat [up3(20ch) | conv2(10ch)] -> m4
    gate_compute_v4<3920, 1960><<<GB, 256, 0, stream>>>(
        up3, conv2, gw[3], gb[3], nw[3], nb[3], epsv[3], graw[3], cs[3]);
    gate_finalize<<<CDIV(BATCH), 256, 0, stream>>>(graw[3], cs[3], kp, gatep[3]);
    moe_conv7<20, 10, 10, 14, 14><<<g4, 256, 0, stream>>>(
        up3, conv2, cw[3], cb[3], gatep[3], m4);
    upsample2<14><<<CDIV(BATCH * 10 * 784), 256, 0, stream>>>(m4, up4, BATCH * 10);

    // ---- layer 5: virtual concat [up4(10ch) | conv1(10ch)] -> m5
    gate_compute_v4<7840, 7840><<<GB, 256, 0, stream>>>(
        up4, conv1, gw[4], gb[4], nw[4], nb[4], epsv[4], graw[4], cs[4]);
    gate_finalize<<<CDIV(BATCH), 256, 0, stream>>>(graw[4], cs[4], kp, gatep[4]);
    moe_conv7<10, 10, 10, 28, 28><<<g5, 256, 0, stream>>>(
        up4, conv1, cw[4], cb[4], gatep[4], m5);

    // ---- final 1x1
    final1x1<<<CDIV(BATCH * 196), 256, 0, stream>>>(m5, wlast, blast, out);
    #undef CDIV
}

// Round 4
// 1382.305 us; speedup vs baseline: 1.7951x; 1.5150x over previous
//
#include <hip/hip_runtime.h>
#include <hip/hip_bf16.h>
#include <math.h>

// ---------------------------------------------------------------------------
// Generalised gated MoE U-net, B=2048, E=4, W=10, fp32 throughout.
// Round 4: conv = 3-row strip x CG=2 couts x 4 experts (~75 VGPR, pipelinable
//   15 tap loads/ci); weights in LDS as [ci][tap][j*4+e] (2x b128 per tap);
//   XCD-aware swizzle so sibling cout-groups share one XCD's L2.
//   Gates = block-per-sample (4 waves, LDS reduce).
// ---------------------------------------------------------------------------

constexpr int BATCH = 2048;

// ---------------- workspace layout (in floats) ----------------
constexpr size_t PADF    = 1024;                       // 4KB guard pads
constexpr size_t F_CONV1 = (size_t)BATCH * 10 * 784;
constexpr size_t F_XPAD  = (size_t)BATCH * 784;
constexpr size_t F_P1    = (size_t)BATCH * 10 * 196;
constexpr size_t F_CONV2 = F_P1;
constexpr size_t F_P2    = (size_t)BATCH * 10 * 49;
constexpr size_t F_CONV3 = (size_t)BATCH * 20 * 49;
constexpr size_t F_UP3   = (size_t)BATCH * 20 * 196;
constexpr size_t F_M4    = F_P1;
constexpr size_t F_UP4   = F_CONV1;
constexpr size_t F_M5    = F_CONV1;

constexpr size_t O_CONV1 = PADF;
constexpr size_t O_Z2    = O_CONV1 + F_CONV1 + PADF;
constexpr size_t O_XPAD  = O_Z2;
constexpr size_t O_P1    = O_XPAD + F_XPAD + PADF;
constexpr size_t O_CONV2 = O_P1 + F_P1 + PADF;
constexpr size_t O_P2    = O_CONV2 + F_CONV2 + PADF;
constexpr size_t O_CONV3 = O_P2 + F_P2 + PADF;
constexpr size_t O_UP3   = O_CONV3 + F_CONV3 + PADF;
constexpr size_t O_M4    = O_UP3 + F_UP3 + PADF;
constexpr size_t O_UP4   = O_Z2;                        // overlays dead xpad..up3
constexpr size_t O_M5    = O_Z2 + F_UP4 + PADF;
constexpr size_t O_GRAW  = O_M5 + F_M5 + PADF;
constexpr size_t O_GATE  = O_GRAW + 5 * (size_t)BATCH * 4;
constexpr size_t O_CS    = O_GATE + 5 * (size_t)BATCH * 4;
constexpr size_t WS_FLOATS = O_CS + 5 * 64 + PADF;

__device__ __forceinline__ float softplusf(float z) {
    return fmaxf(z, 0.0f) + log1pf(expf(-fabsf(z)));
}

__device__ __forceinline__ float4 ld4(const float* p) {
    return *(const float4*)p;
}

constexpr int cdivc(int a, int b) { return (a + b - 1) / b; }
constexpr int pb_of(int H, int W) {
    return (cdivc(BATCH * ((H + 2) / 3) * W, 256) + 7) & ~7;   // mult of 8
}

// ---------------- gate: block per sample, 4 waves split D -------------------
template <int C1HW, int C2HW>
__global__ __launch_bounds__(256) void gate_block_v4(
    const float* __restrict__ x1, const float* __restrict__ x2,
    const float* __restrict__ gw, const float* __restrict__ gb,
    const float* __restrict__ nw, const float* __restrict__ nb,
    const float* __restrict__ eps,
    float* __restrict__ graw, float* __restrict__ colsum)
{
    constexpr int D  = C1HW + C2HW;
    constexpr int DV = D / 4;
    const int b   = blockIdx.x;
    const int tid = threadIdx.x;

    float ga0 = 0.f, ga1 = 0.f, ga2 = 0.f, ga3 = 0.f;
    float na0 = 0.f, na1 = 0.f, na2 = 0.f, na3 = 0.f;

    for (int g = tid; g < DV; g += 256) {
        const int d = g * 4;
        float4 xv;
        if constexpr (C2HW > 0) {
            xv = (d < C1HW) ? ld4(x1 + (size_t)b * C1HW + d)
                            : ld4(x2 + (size_t)b * C2HW + (d - C1HW));
        } else {
            xv = ld4(x1 + (size_t)b * C1HW + d);
        }
        const float xs[4] = {xv.x, xv.y, xv.z, xv.w};
        #pragma unroll
        for (int j = 0; j < 4; ++j) {
            const float val = xs[j];
            const float4 gv = ((const float4*)gw)[d + j];
            const float4 nv = ((const float4*)nw)[d + j];
            ga0 = fmaf(val, gv.x, ga0); ga1 = fmaf(val, gv.y, ga1);
            ga2 = fmaf(val, gv.z, ga2); ga3 = fmaf(val, gv.w, ga3);
            na0 = fmaf(val, nv.x, na0); na1 = fmaf(val, nv.y, na1);
            na2 = fmaf(val, nv.z, na2); na3 = fmaf(val, nv.w, na3);
        }
    }
    #pragma unroll
    for (int m = 32; m >= 1; m >>= 1) {
        ga0 += __shfl_xor(ga0, m, 64); ga1 += __shfl_xor(ga1, m, 64);
        ga2 += __shfl_xor(ga2, m, 64); ga3 += __shfl_xor(ga3, m, 64);
        na0 += __shfl_xor(na0, m, 64); na1 += __shfl_xor(na1, m, 64);
        na2 += __shfl_xor(na2, m, 64); na3 += __shfl_xor(na3, m, 64);
    }
    __shared__ float red[4][8];
    const int wave = tid >> 6, lane = tid & 63;
    if (lane == 0) {
        red[wave][0] = ga0; red[wave][1] = ga1; red[wave][2] = ga2; red[wave][3] = ga3;
        red[wave][4] = na0; red[wave][5] = na1; red[wave][6] = na2; red[wave][7] = na3;
    }
    __syncthreads();
    if (tid == 0) {
        float G[8];
        #pragma unroll
        for (int i = 0; i < 8; ++i)
            G[i] = red[0][i] + red[1][i] + red[2][i] + red[3][i];
        #pragma unroll
        for (int e = 0; e < 4; ++e) {
            const float g = G[e] + gb[e] + eps[e] * softplusf(G[4 + e] + nb[e]);
            graw[b * 4 + e] = g;
            atomicAdd(&colsum[e], g);
        }
    }
}

// scalar variant (D=490 not /4)
template <int D>
__global__ __launch_bounds__(256) void gate_block_s(
    const float* __restrict__ x1,
    const float* __restrict__ gw, const float* __restrict__ gb,
    const float* __restrict__ nw, const float* __restrict__ nb,
    const float* __restrict__ eps,
    float* __restrict__ graw, float* __restrict__ colsum)
{
    const int b   = blockIdx.x;
    const int tid = threadIdx.x;

    float ga0 = 0.f, ga1 = 0.f, ga2 = 0.f, ga3 = 0.f;
    float na0 = 0.f, na1 = 0.f, na2 = 0.f, na3 = 0.f;

    for (int d = tid; d < D; d += 256) {
        const float val = x1[(size_t)b * D + d];
        const float4 gv = ((const float4*)gw)[d];
        const float4 nv = ((const float4*)nw)[d];
        ga0 = fmaf(val, gv.x, ga0); ga1 = fmaf(val, gv.y, ga1);
        ga2 = fmaf(val, gv.z, ga2); ga3 = fmaf(val, gv.w, ga3);
        na0 = fmaf(val, nv.x, na0); na1 = fmaf(val, nv.y, na1);
        na2 = fmaf(val, nv.z, na2); na3 = fmaf(val, nv.w, na3);
    }
    #pragma unroll
    for (int m = 32; m >= 1; m >>= 1) {
        ga0 += __shfl_xor(ga0, m, 64); ga1 += __shfl_xor(ga1, m, 64);
        ga2 += __shfl_xor(ga2, m, 64); ga3 += __shfl_xor(ga3, m, 64);
        na0 += __shfl_xor(na0, m, 64); na1 += __shfl_xor(na1, m, 64);
        na2 += __shfl_xor(na2, m, 64); na3 += __shfl_xor(na3, m, 64);
    }
    __shared__ float red[4][8];
    const int wave = tid >> 6, lane = tid & 63;
    if (lane == 0) {
        red[wave][0] = ga0; red[wave][1] = ga1; red[wave][2] = ga2; red[wave][3] = ga3;
        red[wave][4] = na0; red[wave][5] = na1; red[wave][6] = na2; red[wave][7] = na3;
    }
    __syncthreads();
    if (tid == 0) {
        float G[8];
        #pragma unroll
        for (int i = 0; i < 8; ++i)
            G[i] = red[0][i] + red[1][i] + red[2][i] + red[3][i];
        #pragma unroll
        for (int e = 0; e < 4; ++e) {
            const float g = G[e] + gb[e] + eps[e] * softplusf(G[4 + e] + nb[e]);
            graw[b * 4 + e] = g;
            atomicAdd(&colsum[e], g);
        }
    }
}

// ---------------- gate finalize: top-k mask (by colsum) + masked softmax ----
__global__ __launch_bounds__(256) void gate_finalize(
    const float* __restrict__ graw, const float* __restrict__ colsum,
    const int* __restrict__ kp, float* __restrict__ gate)
{
    const int b = blockIdx.x * 256 + threadIdx.x;
    if (b >= BATCH) return;
    int k = kp[0];
    k = (k < 1) ? 1 : (k > 4 ? 4 : k);

    float cs[4];
    bool sel[4] = {false, false, false, false};
    #pragma unroll
    for (int e = 0; e < 4; ++e) cs[e] = colsum[e];
    for (int it = 0; it < k; ++it) {
        int bi = 0; float bv = -INFINITY;
        #pragma unroll
        for (int e = 0; e < 4; ++e)
            if (!sel[e] && cs[e] > bv) { bv = cs[e]; bi = e; }
        sel[bi] = true;
    }
    float g[4];
    #pragma unroll
    for (int e = 0; e < 4; ++e) {
        float v = graw[b * 4 + e];
        g[e] = sel[e] ? v : 0.0f;   // zero BEFORE softmax (as in reference)
    }
    float m = fmaxf(fmaxf(g[0], g[1]), fmaxf(g[2], g[3]));
    float e0 = expf(g[0] - m), e1 = expf(g[1] - m);
    float e2 = expf(g[2] - m), e3 = expf(g[3] - m);
    float inv = 1.0f / (e0 + e1 + e2 + e3);
    gate[b * 4 + 0] = e0 * inv; gate[b * 4 + 1] = e1 * inv;
    gate[b * 4 + 2] = e2 * inv; gate[b * 4 + 3] = e3 * inv;
}

// ---------------- MoE conv 3x3 SAME + relu + gated expert sum --------------
// Thread = (b, w, 3-row strip) x CG=2 couts x 4 experts. Weights in LDS as
// [ci][tap][j*4+e] -> 2x ds_read_b128 per tap. XCD swizzle: NCG sibling
// cout-groups of one pixel tile run consecutively on the same XCD.
template <int CIN1, int CIN2, int COUT, int H, int W>
__global__ __launch_bounds__(256) void moe_conv3(
    const float* __restrict__ x1, const float* __restrict__ x2,
    const float* __restrict__ cw, const float* __restrict__ cb,
    const float* __restrict__ gate, float* __restrict__ out)
{
    constexpr int CIN = CIN1 + CIN2;
    constexpr int CG  = 2;
    constexpr int NCG = COUT / CG;
    constexpr int HG  = (H + 2) / 3;
    constexpr int TOTAL = BATCH * HG * W;
    constexpr int PB  = pb_of(H, W);          // pixel-tile blocks, mult of 8

    __shared__ __align__(16) float wlds[CIN * 72];   // [ci][k][j*4+e]

    // XCD-aware decomposition: bid = xcd + 8*sub; sub = tl*NCG + cg
    const unsigned bid = blockIdx.x;
    const unsigned xcd = bid & 7u;
    const unsigned sub = bid >> 3;
    const unsigned cg  = sub % NCG;
    const unsigned tl  = sub / NCG;
    const unsigned tile = tl * 8u + xcd;      // < PB by construction
    const int c0 = (int)cg * CG;

    // stage weights: wlds[ci*72 + k*8 + j*4 + e]
    for (int idx = threadIdx.x; idx < CIN * 72; idx += 256) {
        const int ci = idx / 72;
        const int r  = idx % 72;
        const int k  = r / 8;
        const int je = r % 8;
        const int j  = je >> 2;
        const int e  = je & 3;
        wlds[idx] = cw[((size_t)(e * COUT + c0 + j) * CIN + ci) * 9 + k];
    }
    __syncthreads();

    const int t = (int)tile * 256 + threadIdx.x;
    if (t >= TOTAL) return;
    const int b  = t / (HG * W);
    const int r  = t - b * (HG * W);
    const int hg = r / W;
    const int w  = r - hg * W;
    const int h0 = hg * 3;

    // combined masks m[rr][dc] = row-valid * col-valid (precomputed, 15 regs)
    float m[5][3];
    #pragma unroll
    for (int rr = 0; rr < 5; ++rr) {
        const int y = h0 - 1 + rr;
        const float my = (y >= 0 && y < H) ? 1.0f : 0.0f;
        #pragma unroll
        for (int dc = 0; dc < 3; ++dc) {
            const int xx = w - 1 + dc;
            m[rr][dc] = ((xx >= 0 && xx < W) ? 1.0f : 0.0f) * my;
        }
    }
    const int base = (h0 - 1) * W + (w - 1);   // may be negative; pads guard

    float acc[3][CG][4];
    #pragma unroll
    for (int j = 0; j < CG; ++j) {
        #pragma unroll
        for (int e = 0; e < 4; ++e) {
            const float bv = cb[e * COUT + c0 + j];
            #pragma unroll
            for (int rr = 0; rr < 3; ++rr) acc[rr][j][e] = bv;
        }
    }

    const float* xb1 = x1 + (size_t)b * CIN1 * (H * W);
    const float* xb2 = (CIN2 > 0) ? (x2 + (size_t)b * CIN2 * (H * W)) : nullptr;

    for (int ci = 0; ci < CIN; ++ci) {
        const float* xp;
        if constexpr (CIN2 > 0) {
            xp = (ci < CIN1) ? (xb1 + ci * (H * W)) : (xb2 + (ci - CIN1) * (H * W));
        } else {
            xp = xb1 + ci * (H * W);
        }
        // 15 tap loads, single base + immediate offsets
        float v[5][3];
        #pragma unroll
        for (int rr = 0; rr < 5; ++rr) {
            #pragma unroll
            for (int dc = 0; dc < 3; ++dc) {
                v[rr][dc] = xp[base + rr * W + dc] * m[rr][dc];
            }
        }
        const float4* wp = (const float4*)&wlds[ci * 72];
        #pragma unroll
        for (int k = 0; k < 9; ++k) {
            const float4 wA = wp[k * 2];       // j=0, e=0..3
            const float4 wB = wp[k * 2 + 1];   // j=1, e=0..3
            const int kh = k / 3, kw = k % 3;
            #pragma unroll
            for (int rr = 0; rr < 3; ++rr) {
                const float tap = v[rr + kh][kw];
                acc[rr][0][0] = fmaf(tap, wA.x, acc[rr][0][0]);
                acc[rr][0][1] = fmaf(tap, wA.y, acc[rr][0][1]);
                acc[rr][0][2] = fmaf(tap, wA.z, acc[rr][0][2]);
                acc[rr][0][3] = fmaf(tap, wA.w, acc[rr][0][3]);
                acc[rr][1][0] = fmaf(tap, wB.x, acc[rr][1][0]);
                acc[rr][1][1] = fmaf(tap, wB.y, acc[rr][1][1]);
                acc[rr][1][2] = fmaf(tap, wB.z, acc[rr][1][2]);
                acc[rr][1][3] = fmaf(tap, wB.w, acc[rr][1][3]);
            }
        }
    }

    const float4 gv = ld4(gate + b * 4);
    #pragma unroll
    for (int j = 0; j < CG; ++j) {
        float* op = out + ((size_t)b * COUT + c0 + j) * (H * W) + h0 * W + w;
        #pragma unroll
        for (int rr = 0; rr < 3; ++rr) {
            if (h0 + rr < H) {
                const float s = gv.x * fmaxf(acc[rr][j][0], 0.f)
                              + gv.y * fmaxf(acc[rr][j][1], 0.f)
                              + gv.z * fmaxf(acc[rr][j][2], 0.f)
                              + gv.w * fmaxf(acc[rr][j][3], 0.f);
                op[rr * W] = s;
            }
        }
    }
}

// ---------------- 2x2 maxpool stride 2 ----------------
template <int N>
__global__ __launch_bounds__(256) void maxpool2(
    const float* __restrict__ in, float* __restrict__ out, int BC)
{
    constexpr int N2 = N / 2;
    const int idx = blockIdx.x * 256 + threadIdx.x;
    const int total = BC * N2 * N2;
    if (idx >= total) return;
    const int j = idx % N2;
    int tmp = idx / N2;
    const int i = tmp % N2;
    const int bc = tmp / N2;
    const float* p = in + (size_t)bc * N * N + (2 * i) * N + 2 * j;
    out[idx] = fmaxf(fmaxf(p[0], p[1]), fmaxf(p[N], p[N + 1]));
}

// ---------------- bilinear x2 upsample, align_corners=True ----------------
template <int N>
__global__ __launch_bounds__(256) void upsample2(
    const float* __restrict__ in, float* __restrict__ out, int BC)
{
    constexpr int M = 2 * N;
    const int idx = blockIdx.x * 256 + threadIdx.x;
    const int total = BC * M * M;
    if (idx >= total) return;
    const int x = idx % M;
    int tmp = idx / M;
    const int y = tmp % M;
    const int bc = tmp / M;
    const float scale = (float)((double)(N - 1) / (double)(M - 1));
    const float cy = (float)y * scale;
    const float cx = (float)x * scale;
    const int iy0 = (int)floorf(cy);
    const int ix0 = (int)floorf(cx);
    const int iy1 = min(iy0 + 1, N - 1);
    const int ix1 = min(ix0 + 1, N - 1);
    const float wy = cy - (float)iy0;
    const float wx = cx - (float)ix0;
    const float* p = in + (size_t)bc * N * N;
    const float v00 = p[iy0 * N + ix0], v01 = p[iy0 * N + ix1];
    const float v10 = p[iy1 * N + ix0], v11 = p[iy1 * N + ix1];
    const float a0 = v00 * (1.0f - wy) + v10 * wy;
    const float a1 = v01 * (1.0f - wy) + v11 * wy;
    out[idx] = a0 * (1.0f - wx) + a1 * wx;
}

// ---------------- final 1x1 conv (float4) ----------------
__global__ __launch_bounds__(256) void final1x1(
    const float* __restrict__ h, const float* __restrict__ wl,
    const float* __restrict__ bl, float* __restrict__ out)
{
    const int idx = blockIdx.x * 256 + threadIdx.x;
    const int total = BATCH * 196;
    if (idx >= total) return;
    const int s4 = idx % 196;
    const int b = idx / 196;
    const float b0 = bl[0];
    float4 acc = {b0, b0, b0, b0};
    #pragma unroll
    for (int c = 0; c < 10; ++c) {
        const float wv = wl[c];
        const float4 v = ld4(h + ((size_t)b * 10 + c) * 784 + s4 * 4);
        acc.x = fmaf(v.x, wv, acc.x); acc.y = fmaf(v.y, wv, acc.y);
        acc.z = fmaf(v.z, wv, acc.z); acc.w = fmaf(v.w, wv, acc.w);
    }
    ((float4*)out)[idx] = acc;
}

// ---------------------------------------------------------------------------
extern "C" void kernel_launch(void* const* d_in, const int* in_sizes, int n_in,
                              void* d_out, int out_size, void* d_ws, size_t ws_size,
                              hipStream_t stream)
{
    const float* x = (const float*)d_in[0];
    const float* cw[5]; const float* cb[5]; const float* gw[5]; const float* gb[5];
    const float* nw[5]; const float* nb[5]; const float* epsv[5];
    for (int l = 0; l < 5; ++l) {
        cw[l]   = (const float*)d_in[1 + 7 * l + 0];
        cb[l]   = (const float*)d_in[1 + 7 * l + 1];
        gw[l]   = (const float*)d_in[1 + 7 * l + 2];
        gb[l]   = (const float*)d_in[1 + 7 * l + 3];
        nw[l]   = (const float*)d_in[1 + 7 * l + 4];
        nb[l]   = (const float*)d_in[1 + 7 * l + 5];
        epsv[l] = (const float*)d_in[1 + 7 * l + 6];
    }
    const float* wlast = (const float*)d_in[36];
    const float* blast = (const float*)d_in[37];
    const int*   kp    = (const int*)d_in[38];
    float* out = (float*)d_out;
    float* ws  = (float*)d_ws;

    float* conv1 = ws + O_CONV1;
    float* xpad  = ws + O_XPAD;
    float* p1    = ws + O_P1;
    float* conv2 = ws + O_CONV2;
    float* p2    = ws + O_P2;
    float* conv3 = ws + O_CONV3;
    float* up3   = ws + O_UP3;
    float* m4    = ws + O_M4;
    float* up4   = ws + O_UP4;
    float* m5    = ws + O_M5;
    float* graw[5]; float* gatep[5]; float* cs[5];
    for (int l = 0; l < 5; ++l) {
        graw[l]  = ws + O_GRAW + (size_t)l * BATCH * 4;
        gatep[l] = ws + O_GATE + (size_t)l * BATCH * 4;
        cs[l]    = ws + O_CS + (size_t)l * 64;
    }

    hipMemsetAsync(ws + O_CS, 0, 5 * 64 * sizeof(float), stream);
    hipMemcpyAsync(xpad, x, (size_t)BATCH * 784 * sizeof(float),
                   hipMemcpyDeviceToDevice, stream);

    #define CDIV(a) (((a) + 255) / 256)
    // conv grids: PB * NCG (PB multiple of 8)
    const int g1 = pb_of(28, 28) * 5;   // L1: COUT=10
    const int g2 = pb_of(14, 14) * 5;   // L2
    const int g3 = pb_of(7, 7)   * 10;  // L3: COUT=20
    const int g4 = pb_of(14, 14) * 5;   // L4
    const int g5 = pb_of(28, 28) * 5;   // L5

    // ---- layer 1: x [B,1,28,28] -> conv1 [B,10,28,28]
    gate_block_v4<784, 0><<<BATCH, 256, 0, stream>>>(
        x, nullptr, gw[0], gb[0], nw[0], nb[0], epsv[0], graw[0], cs[0]);
    gate_finalize<<<CDIV(BATCH), 256, 0, stream>>>(graw[0], cs[0], kp, gatep[0]);
    moe_conv3<1, 0, 10, 28, 28><<<g1, 256, 0, stream>>>(
        xpad, nullptr, cw[0], cb[0], gatep[0], conv1);
    maxpool2<28><<<CDIV(BATCH * 10 * 196), 256, 0, stream>>>(conv1, p1, BATCH * 10);

    // ---- layer 2: p1 [B,10,14,14] -> conv2 [B,10,14,14]
    gate_block_v4<1960, 0><<<BATCH, 256, 0, stream>>>(
        p1, nullptr, gw[1], gb[1], nw[1], nb[1], epsv[1], graw[1], cs[1]);
    gate_finalize<<<CDIV(BATCH), 256, 0, stream>>>(graw[1], cs[1], kp, gatep[1]);
    moe_conv3<10, 0, 10, 14, 14><<<g2, 256, 0, stream>>>(
        p1, nullptr, cw[1], cb[1], gatep[1], conv2);
    maxpool2<14><<<CDIV(BATCH * 10 * 49), 256, 0, stream>>>(conv2, p2, BATCH * 10);

    // ---- layer 3: p2 [B,10,7,7] -> conv3 [B,20,7,7]  (D=490 scalar)
    gate_block_s<490><<<BATCH, 256, 0, stream>>>(
        p2, gw[2], gb[2], nw[2], nb[2], epsv[2], graw[2], cs[2]);
    gate_finalize<<<CDIV(BATCH), 256, 0, stream>>>(graw[2], cs[2], kp, gatep[2]);
    moe_conv3<10, 0, 20, 7, 7><<<g3, 256, 0, stream>>>(
        p2, nullptr, cw[2], cb[2], gatep[2], conv3);
    upsample2<7><<<CDIV(BATCH * 20 * 196), 256, 0, stream>>>(conv3, up3, BATCH * 20);

    // ---- layer 4: virtual concat [up3(20ch) | conv2(10ch)] -> m4
    gate_block_v4<3920, 1960><<<BATCH, 256, 0, stream>>>(
        up3, conv2, gw[3], gb[3], nw[3], nb[3], epsv[3], graw[3], cs[3]);
    gate_finalize<<<CDIV(BATCH), 256, 0, stream>>>(graw[3], cs[3], kp, gatep[3]);
    moe_conv3<20, 10, 10, 14, 14><<<g4, 256, 0, stream>>>(
        up3, conv2, cw[3], cb[3], gatep[3], m4);
    upsample2<14><<<CDIV(BATCH * 10 * 784), 256, 0, stream>>>(m4, up4, BATCH * 10);

    // ---- layer 5: virtual concat [up4(10ch) | conv1(10ch)] -> m5
    gate_block_v4<7840, 7840><<<BATCH, 256, 0, stream>>>(
        up4, conv1, gw[4], gb[4], nw[4], nb[4], epsv[4], graw[4], cs[4]);
    gate_finalize<<<CDIV(BATCH), 256, 0, stream>>>(graw[4], cs[4], kp, gatep[4]);
    moe_conv3<10, 10, 10, 28, 28><<<g5, 256, 0, stream>>>(
        up4, conv1, cw[4], cb[4], gatep[4], m5);

    // ---- final 1x1
    final1x1<<<CDIV(BATCH * 196), 256, 0, stream>>>(m5, wlast, blast, out);
    #undef CDIV
}

// Round 5
// 1320.031 us; speedup vs baseline: 1.8798x; 1.0472x over previous
//
#include <hip/hip_runtime.h>
#include <hip/hip_bf16.h>
#include <math.h>

// ---------------------------------------------------------------------------
// Generalised gated MoE U-net, B=2048, E=4, W=10, fp32 throughout.
// Round 5: conv = 4-row strip x CG=2 couts x 4 experts with explicit
//   ping-pong tap prefetch (software pipeline over ci); gate finalize fused
//   into conv preamble; maxpool fused into conv epilogue (shfl_xor pairing);
//   XCD-aware swizzle retained. 15 dispatches total (was 22).
// ---------------------------------------------------------------------------

constexpr int BATCH = 2048;

// ---------------- workspace layout (in floats) ----------------
constexpr size_t PADF    = 1024;                       // 4KB guard pads
constexpr size_t F_CONV1 = (size_t)BATCH * 10 * 784;
constexpr size_t F_XPAD  = (size_t)BATCH * 784;
constexpr size_t F_P1    = (size_t)BATCH * 10 * 196;
constexpr size_t F_CONV2 = F_P1;
constexpr size_t F_P2    = (size_t)BATCH * 10 * 49;
constexpr size_t F_CONV3 = (size_t)BATCH * 20 * 49;
constexpr size_t F_UP3   = (size_t)BATCH * 20 * 196;
constexpr size_t F_M4    = F_P1;
constexpr size_t F_UP4   = F_CONV1;
constexpr size_t F_M5    = F_CONV1;

constexpr size_t O_CONV1 = PADF;
constexpr size_t O_Z2    = O_CONV1 + F_CONV1 + PADF;
constexpr size_t O_XPAD  = O_Z2;
constexpr size_t O_P1    = O_XPAD + F_XPAD + PADF;
constexpr size_t O_CONV2 = O_P1 + F_P1 + PADF;
constexpr size_t O_P2    = O_CONV2 + F_CONV2 + PADF;
constexpr size_t O_CONV3 = O_P2 + F_P2 + PADF;
constexpr size_t O_UP3   = O_CONV3 + F_CONV3 + PADF;
constexpr size_t O_M4    = O_UP3 + F_UP3 + PADF;
constexpr size_t O_UP4   = O_Z2;                        // overlays dead xpad..up3
constexpr size_t O_M5    = O_Z2 + F_UP4 + PADF;
constexpr size_t O_GRAW  = O_M5 + F_M5 + PADF;
constexpr size_t O_CS    = O_GRAW + 5 * (size_t)BATCH * 4;  // 5 x 64
constexpr size_t WS_FLOATS = O_CS + 5 * 64 + PADF;

__device__ __forceinline__ float softplusf(float z) {
    return fmaxf(z, 0.0f) + log1pf(expf(-fabsf(z)));
}

__device__ __forceinline__ float4 ld4(const float* p) {
    return *(const float4*)p;
}

constexpr int cdivc(int a, int b) { return (a + b - 1) / b; }
constexpr int pb4(int H, int W) {          // 4-row strips; exact mult of 256
    return cdivc(BATCH * ((H + 3) / 4) * W, 256);
}

// ---------------- gate: block per sample, float4 path ----------------------
template <int C1HW, int C2HW>
__global__ __launch_bounds__(256) void gate_block_v4(
    const float* __restrict__ x1, const float* __restrict__ x2,
    const float* __restrict__ gw, const float* __restrict__ gb,
    const float* __restrict__ nw, const float* __restrict__ nb,
    const float* __restrict__ eps,
    float* __restrict__ graw, float* __restrict__ colsum)
{
    constexpr int DV = (C1HW + C2HW) / 4;
    const int b   = blockIdx.x;
    const int tid = threadIdx.x;

    float ga0 = 0.f, ga1 = 0.f, ga2 = 0.f, ga3 = 0.f;
    float na0 = 0.f, na1 = 0.f, na2 = 0.f, na3 = 0.f;

    for (int g = tid; g < DV; g += 256) {
        const int d = g * 4;
        float4 xv;
        if constexpr (C2HW > 0) {
            xv = (d < C1HW) ? ld4(x1 + (size_t)b * C1HW + d)
                            : ld4(x2 + (size_t)b * C2HW + (d - C1HW));
        } else {
            xv = ld4(x1 + (size_t)b * C1HW + d);
        }
        const float xs[4] = {xv.x, xv.y, xv.z, xv.w};
        #pragma unroll
        for (int j = 0; j < 4; ++j) {
            const float val = xs[j];
            const float4 gv = ((const float4*)gw)[d + j];
            const float4 nv = ((const float4*)nw)[d + j];
            ga0 = fmaf(val, gv.x, ga0); ga1 = fmaf(val, gv.y, ga1);
            ga2 = fmaf(val, gv.z, ga2); ga3 = fmaf(val, gv.w, ga3);
            na0 = fmaf(val, nv.x, na0); na1 = fmaf(val, nv.y, na1);
            na2 = fmaf(val, nv.z, na2); na3 = fmaf(val, nv.w, na3);
        }
    }
    #pragma unroll
    for (int m = 32; m >= 1; m >>= 1) {
        ga0 += __shfl_xor(ga0, m, 64); ga1 += __shfl_xor(ga1, m, 64);
        ga2 += __shfl_xor(ga2, m, 64); ga3 += __shfl_xor(ga3, m, 64);
        na0 += __shfl_xor(na0, m, 64); na1 += __shfl_xor(na1, m, 64);
        na2 += __shfl_xor(na2, m, 64); na3 += __shfl_xor(na3, m, 64);
    }
    __shared__ float red[4][8];
    const int wave = tid >> 6, lane = tid & 63;
    if (lane == 0) {
        red[wave][0] = ga0; red[wave][1] = ga1; red[wave][2] = ga2; red[wave][3] = ga3;
        red[wave][4] = na0; red[wave][5] = na1; red[wave][6] = na2; red[wave][7] = na3;
    }
    __syncthreads();
    if (tid == 0) {
        float G[8];
        #pragma unroll
        for (int i = 0; i < 8; ++i)
            G[i] = red[0][i] + red[1][i] + red[2][i] + red[3][i];
        #pragma unroll
        for (int e = 0; e < 4; ++e) {
            const float g = G[e] + gb[e] + eps[e] * softplusf(G[4 + e] + nb[e]);
            graw[b * 4 + e] = g;
            atomicAdd(&colsum[e], g);
        }
    }
}

// scalar variant (D=490)
template <int D>
__global__ __launch_bounds__(256) void gate_block_s(
    const float* __restrict__ x1,
    const float* __restrict__ gw, const float* __restrict__ gb,
    const float* __restrict__ nw, const float* __restrict__ nb,
    const float* __restrict__ eps,
    float* __restrict__ graw, float* __restrict__ colsum)
{
    const int b   = blockIdx.x;
    const int tid = threadIdx.x;

    float ga0 = 0.f, ga1 = 0.f, ga2 = 0.f, ga3 = 0.f;
    float na0 = 0.f, na1 = 0.f, na2 = 0.f, na3 = 0.f;

    for (int d = tid; d < D; d += 256) {
        const float val = x1[(size_t)b * D + d];
        const float4 gv = ((const float4*)gw)[d];
        const float4 nv = ((const float4*)nw)[d];
        ga0 = fmaf(val, gv.x, ga0); ga1 = fmaf(val, gv.y, ga1);
        ga2 = fmaf(val, gv.z, ga2); ga3 = fmaf(val, gv.w, ga3);
        na0 = fmaf(val, nv.x, na0); na1 = fmaf(val, nv.y, na1);
        na2 = fmaf(val, nv.z, na2); na3 = fmaf(val, nv.w, na3);
    }
    #pragma unroll
    for (int m = 32; m >= 1; m >>= 1) {
        ga0 += __shfl_xor(ga0, m, 64); ga1 += __shfl_xor(ga1, m, 64);
        ga2 += __shfl_xor(ga2, m, 64); ga3 += __shfl_xor(ga3, m, 64);
        na0 += __shfl_xor(na0, m, 64); na1 += __shfl_xor(na1, m, 64);
        na2 += __shfl_xor(na2, m, 64); na3 += __shfl_xor(na3, m, 64);
    }
    __shared__ float red[4][8];
    const int wave = tid >> 6, lane = tid & 63;
    if (lane == 0) {
        red[wave][0] = ga0; red[wave][1] = ga1; red[wave][2] = ga2; red[wave][3] = ga3;
        red[wave][4] = na0; red[wave][5] = na1; red[wave][6] = na2; red[wave][7] = na3;
    }
    __syncthreads();
    if (tid == 0) {
        float G[8];
        #pragma unroll
        for (int i = 0; i < 8; ++i)
            G[i] = red[0][i] + red[1][i] + red[2][i] + red[3][i];
        #pragma unroll
        for (int e = 0; e < 4; ++e) {
            const float g = G[e] + gb[e] + eps[e] * softplusf(G[4 + e] + nb[e]);
            graw[b * 4 + e] = g;
            atomicAdd(&colsum[e], g);
        }
    }
}

// ---------------- MoE conv 3x3 SAME + relu + gated sum (+fused pool) -------
// Thread = (b, w, 4-row strip) x CG=2 couts x 4 experts. Ping-pong tap
// prefetch over ci. Gate finalize (top-k + masked softmax) inlined.
// POOL=1: 2x2 maxpool fused via shfl_xor(1) (lane parity == w parity).
template <int CIN1, int CIN2, int COUT, int H, int W, int POOL>
__global__ __launch_bounds__(256) void moe_conv4(
    const float* __restrict__ x1, const float* __restrict__ x2,
    const float* __restrict__ cw, const float* __restrict__ cb,
    const float* __restrict__ graw, const float* __restrict__ colsum,
    const int* __restrict__ kp,
    float* __restrict__ out, float* __restrict__ pout)
{
    constexpr int CIN = CIN1 + CIN2;
    constexpr int CG  = 2;
    constexpr int NCG = COUT / CG;
    constexpr int HG  = (H + 3) / 4;
    constexpr int TOTAL = BATCH * HG * W;

    __shared__ __align__(16) float wlds[CIN * 72];   // [ci][k][j*4+e]

    const unsigned bid = blockIdx.x;
    const unsigned xcd = bid & 7u;
    const unsigned sub = bid >> 3;
    const unsigned cg  = sub % NCG;
    const unsigned tl  = sub / NCG;
    const unsigned tile = tl * 8u + xcd;
    const int c0 = (int)cg * CG;

    for (int idx = threadIdx.x; idx < CIN * 72; idx += 256) {
        const int ci = idx / 72;
        const int r  = idx % 72;
        const int k  = r / 8;
        const int je = r % 8;
        wlds[idx] = cw[((size_t)((je & 3) * COUT + c0 + (je >> 2)) * CIN + ci) * 9 + k];
    }
    __syncthreads();

    const int t = (int)tile * 256 + (int)threadIdx.x;
    if (t >= TOTAL) return;                    // TOTAL % 256 == 0: never taken
    const int b  = t / (HG * W);
    const int r  = t - b * (HG * W);
    const int hg = r / W;
    const int w  = r - hg * W;
    const int h0 = hg * 4;

    // ---- inline gate finalize: top-k (by colsum) + masked softmax ----
    float gt[4];
    {
        int k = kp[0];
        k = (k < 1) ? 1 : (k > 4 ? 4 : k);
        float cs[4], gr[4];
        bool sel[4] = {false, false, false, false};
        #pragma unroll
        for (int e = 0; e < 4; ++e) { cs[e] = colsum[e]; gr[e] = graw[b * 4 + e]; }
        for (int it = 0; it < k; ++it) {
            int bi = 0; float bv = -INFINITY;
            #pragma unroll
            for (int e = 0; e < 4; ++e)
                if (!sel[e] && cs[e] > bv) { bv = cs[e]; bi = e; }
            sel[bi] = true;
        }
        float g[4];
        #pragma unroll
        for (int e = 0; e < 4; ++e) g[e] = sel[e] ? gr[e] : 0.0f;
        const float mx = fmaxf(fmaxf(g[0], g[1]), fmaxf(g[2], g[3]));
        const float e0 = expf(g[0] - mx), e1 = expf(g[1] - mx);
        const float e2 = expf(g[2] - mx), e3 = expf(g[3] - mx);
        const float inv = 1.0f / (e0 + e1 + e2 + e3);
        gt[0] = e0 * inv; gt[1] = e1 * inv; gt[2] = e2 * inv; gt[3] = e3 * inv;
    }

    // combined tap masks (6 rows x 3 cols)
    float m[6][3];
    #pragma unroll
    for (int rr = 0; rr < 6; ++rr) {
        const int y = h0 - 1 + rr;
        const float my = (y >= 0 && y < H) ? 1.0f : 0.0f;
        #pragma unroll
        for (int dc = 0; dc < 3; ++dc) {
            const int xx = w - 1 + dc;
            m[rr][dc] = ((xx >= 0 && xx < W) ? 1.0f : 0.0f) * my;
        }
    }
    const int base = (h0 - 1) * W + (w - 1);   // may be negative; pads guard

    float acc[4][CG][4];
    #pragma unroll
    for (int j = 0; j < CG; ++j) {
        #pragma unroll
        for (int e = 0; e < 4; ++e) {
            const float bv = cb[e * COUT + c0 + j];
            #pragma unroll
            for (int rr = 0; rr < 4; ++rr) acc[rr][j][e] = bv;
        }
    }

    const float* xb1 = x1 + (size_t)b * CIN1 * (H * W);
    const float* xb2 = (CIN2 > 0) ? (x2 + (size_t)b * CIN2 * (H * W)) : nullptr;

    auto xplane = [&](int ci) -> const float* {
        if constexpr (CIN2 > 0)
            return (ci < CIN1) ? (xb1 + ci * (H * W)) : (xb2 + (ci - CIN1) * (H * W));
        else
            return xb1 + ci * (H * W);
    };
    auto load_taps = [&](int ci, float v[6][3]) {
        const float* xp = xplane(ci);
        #pragma unroll
        for (int rr = 0; rr < 6; ++rr)
            #pragma unroll
            for (int dc = 0; dc < 3; ++dc)
                v[rr][dc] = xp[base + rr * W + dc];
    };
    auto fma_taps = [&](int ci, const float v[6][3]) {
        float mv[6][3];
        #pragma unroll
        for (int rr = 0; rr < 6; ++rr)
            #pragma unroll
            for (int dc = 0; dc < 3; ++dc)
                mv[rr][dc] = v[rr][dc] * m[rr][dc];
        const float4* wp = (const float4*)&wlds[ci * 72];
        #pragma unroll
        for (int k = 0; k < 9; ++k) {
            const float4 wA = wp[k * 2];
            const float4 wB = wp[k * 2 + 1];
            const int kh = k / 3, kw = k % 3;
            #pragma unroll
            for (int rr = 0; rr < 4; ++rr) {
                const float tap = mv[rr + kh][kw];
                acc[rr][0][0] = fmaf(tap, wA.x, acc[rr][0][0]);
                acc[rr][0][1] = fmaf(tap, wA.y, acc[rr][0][1]);
                acc[rr][0][2] = fmaf(tap, wA.z, acc[rr][0][2]);
                acc[rr][0][3] = fmaf(tap, wA.w, acc[rr][0][3]);
                acc[rr][1][0] = fmaf(tap, wB.x, acc[rr][1][0]);
                acc[rr][1][1] = fmaf(tap, wB.y, acc[rr][1][1]);
                acc[rr][1][2] = fmaf(tap, wB.z, acc[rr][1][2]);
                acc[rr][1][3] = fmaf(tap, wB.w, acc[rr][1][3]);
            }
        }
    };

    // software pipeline: ping-pong prefetch one ci ahead
    float vA[6][3], vB[6][3];
    load_taps(0, vA);
    #pragma unroll 1
    for (int ci = 0; ci + 2 <= CIN; ci += 2) {
        load_taps(ci + 1, vB);
        fma_taps(ci, vA);
        if (ci + 2 < CIN) load_taps(ci + 2, vA);
        fma_taps(ci + 1, vB);
    }
    if constexpr (CIN & 1) {
        fma_taps(CIN - 1, vA);
    }

    // ---- epilogue: relu + gated sum, conv write, optional fused 2x2 pool ----
    float s[4][CG];
    #pragma unroll
    for (int rr = 0; rr < 4; ++rr)
        #pragma unroll
        for (int j = 0; j < CG; ++j)
            s[rr][j] = gt[0] * fmaxf(acc[rr][j][0], 0.f)
                     + gt[1] * fmaxf(acc[rr][j][1], 0.f)
                     + gt[2] * fmaxf(acc[rr][j][2], 0.f)
                     + gt[3] * fmaxf(acc[rr][j][3], 0.f);

    #pragma unroll
    for (int j = 0; j < CG; ++j) {
        float* op = out + ((size_t)b * COUT + c0 + j) * (H * W) + h0 * W + w;
        #pragma unroll
        for (int rr = 0; rr < 4; ++rr)
            if (h0 + rr < H) op[rr * W] = s[rr][j];
    }

    if constexpr (POOL) {
        constexpr int H2 = H / 2, W2 = W / 2;
        #pragma unroll
        for (int j = 0; j < CG; ++j) {
            float cm0 = fmaxf(s[0][j], s[1][j]);
            float cm1 = fmaxf(s[2][j], s[3][j]);
            const float o0 = fmaxf(cm0, __shfl_xor(cm0, 1, 64));
            const float o1 = fmaxf(cm1, __shfl_xor(cm1, 1, 64));
            if ((w & 1) == 0) {
                const int pr0 = h0 >> 1;
                float* pp = pout + ((size_t)b * COUT + c0 + j) * (H2 * W2) + (w >> 1);
                if (pr0     < H2) pp[pr0 * W2]       = o0;
                if (pr0 + 1 < H2) pp[(pr0 + 1) * W2] = o1;
            }
        }
    }
}

// ---------------- bilinear x2 upsample, align_corners=True ----------------
template <int N>
__global__ __launch_bounds__(256) void upsample2(
    const float* __restrict__ in, float* __restrict__ out, int BC)
{
    constexpr int M = 2 * N;
    const int idx = blockIdx.x * 256 + threadIdx.x;
    const int total = BC * M * M;
    if (idx >= total) return;
    const int x = idx % M;
    int tmp = idx / M;
    const int y = tmp % M;
    const int bc = tmp / M;
    const float scale = (float)((double)(N - 1) / (double)(M - 1));
    const float cy = (float)y * scale;
    const float cx = (float)x * scale;
    const int iy0 = (int)floorf(cy);
    const int ix0 = (int)floorf(cx);
    const int iy1 = min(iy0 + 1, N - 1);
    const int ix1 = min(ix0 + 1, N - 1);
    const float wy = cy - (float)iy0;
    const float wx = cx - (float)ix0;
    const float* p = in + (size_t)bc * N * N;
    const float v00 = p[iy0 * N + ix0], v01 = p[iy0 * N + ix1];
    const float v10 = p[iy1 * N + ix0], v11 = p[iy1 * N + ix1];
    const float a0 = v00 * (1.0f - wy) + v10 * wy;
    const float a1 = v01 * (1.0f - wy) + v11 * wy;
    out[idx] = a0 * (1.0f - wx) + a1 * wx;
}

// ---------------- final 1x1 conv (float4) ----------------
__global__ __launch_bounds__(256) void final1x1(
    const float* __restrict__ h, const float* __restrict__ wl,
    const float* __restrict__ bl, float* __restrict__ out)
{
    const int idx = blockIdx.x * 256 + threadIdx.x;
    const int total = BATCH * 196;
    if (idx >= total) return;
    const int s4 = idx % 196;
    const int b = idx / 196;
    const float b0 = bl[0];
    float4 acc = {b0, b0, b0, b0};
    #pragma unroll
    for (int c = 0; c < 10; ++c) {
        const float wv = wl[c];
        const float4 v = ld4(h + ((size_t)b * 10 + c) * 784 + s4 * 4);
        acc.x = fmaf(v.x, wv, acc.x); acc.y = fmaf(v.y, wv, acc.y);
        acc.z = fmaf(v.z, wv, acc.z); acc.w = fmaf(v.w, wv, acc.w);
    }
    ((float4*)out)[idx] = acc;
}

// ---------------------------------------------------------------------------
extern "C" void kernel_launch(void* const* d_in, const int* in_sizes, int n_in,
                              void* d_out, int out_size, void* d_ws, size_t ws_size,
                              hipStream_t stream)
{
    const float* x = (const float*)d_in[0];
    const float* cw[5]; const float* cb[5]; const float* gw[5]; const float* gb[5];
    const float* nw[5]; const float* nb[5]; const float* epsv[5];
    for (int l = 0; l < 5; ++l) {
        cw[l]   = (const float*)d_in[1 + 7 * l + 0];
        cb[l]   = (const float*)d_in[1 + 7 * l + 1];
        gw[l]   = (const float*)d_in[1 + 7 * l + 2];
        gb[l]   = (const float*)d_in[1 + 7 * l + 3];
        nw[l]   = (const float*)d_in[1 + 7 * l + 4];
        nb[l]   = (const float*)d_in[1 + 7 * l + 5];
        epsv[l] = (const float*)d_in[1 + 7 * l + 6];
    }
    const float* wlast = (const float*)d_in[36];
    const float* blast = (const float*)d_in[37];
    const int*   kp    = (const int*)d_in[38];
    float* out = (float*)d_out;
    float* ws  = (float*)d_ws;

    float* conv1 = ws + O_CONV1;
    float* xpad  = ws + O_XPAD;
    float* p1    = ws + O_P1;
    float* conv2 = ws + O_CONV2;
    float* p2    = ws + O_P2;
    float* conv3 = ws + O_CONV3;
    float* up3   = ws + O_UP3;
    float* m4    = ws + O_M4;
    float* up4   = ws + O_UP4;
    float* m5    = ws + O_M5;
    float* graw[5]; float* cs[5];
    for (int l = 0; l < 5; ++l) {
        graw[l] = ws + O_GRAW + (size_t)l * BATCH * 4;
        cs[l]   = ws + O_CS + (size_t)l * 64;
    }

    hipMemsetAsync(ws + O_CS, 0, 5 * 64 * sizeof(float), stream);
    hipMemcpyAsync(xpad, x, (size_t)BATCH * 784 * sizeof(float),
                   hipMemcpyDeviceToDevice, stream);

    #define CDIV(a) (((a) + 255) / 256)
    const int g1 = pb4(28, 28) * 5;   // 1568 * 5
    const int g2 = pb4(14, 14) * 5;   //  448 * 5
    const int g3 = pb4(7, 7)   * 10;  //  112 * 10
    const int g4 = pb4(14, 14) * 5;
    const int g5 = pb4(28, 28) * 5;

    // ---- layer 1: x [B,1,28,28] -> conv1 + p1 (fused pool)
    gate_block_v4<784, 0><<<BATCH, 256, 0, stream>>>(
        x, nullptr, gw[0], gb[0], nw[0], nb[0], epsv[0], graw[0], cs[0]);
    moe_conv4<1, 0, 10, 28, 28, 1><<<g1, 256, 0, stream>>>(
        xpad, nullptr, cw[0], cb[0], graw[0], cs[0], kp, conv1, p1);

    // ---- layer 2: p1 -> conv2 + p2 (fused pool)
    gate_block_v4<1960, 0><<<BATCH, 256, 0, stream>>>(
        p1, nullptr, gw[1], gb[1], nw[1], nb[1], epsv[1], graw[1], cs[1]);
    moe_conv4<10, 0, 10, 14, 14, 1><<<g2, 256, 0, stream>>>(
        p1, nullptr, cw[1], cb[1], graw[1], cs[1], kp, conv2, p2);

    // ---- layer 3: p2 -> conv3 -> up3
    gate_block_s<490><<<BATCH, 256, 0, stream>>>(
        p2, gw[2], gb[2], nw[2], nb[2], epsv[2], graw[2], cs[2]);
    moe_conv4<10, 0, 20, 7, 7, 0><<<g3, 256, 0, stream>>>(
        p2, nullptr, cw[2], cb[2], graw[2], cs[2], kp, conv3, nullptr);
    upsample2<7><<<CDIV(BATCH * 20 * 196), 256, 0, stream>>>(conv3, up3, BATCH * 20);

    // ---- layer 4: [up3 | conv2] -> m4 -> up4
    gate_block_v4<3920, 1960><<<BATCH, 256, 0, stream>>>(
        up3, conv2, gw[3], gb[3], nw[3], nb[3], epsv[3], graw[3], cs[3]);
    moe_conv4<20, 10, 10, 14, 14, 0><<<g4, 256, 0, stream>>>(
        up3, conv2, cw[3], cb[3], graw[3], cs[3], kp, m4, nullptr);
    upsample2<14><<<CDIV(BATCH * 10 * 784), 256, 0, stream>>>(m4, up4, BATCH * 10);

    // ---- layer 5: [up4 | conv1] -> m5
    gate_block_v4<7840, 7840><<<BATCH, 256, 0, stream>>>(
        up4, conv1, gw[4], gb[4], nw[4], nb[4], epsv[4], graw[4], cs[4]);
    moe_conv4<10, 10, 10, 28, 28, 0><<<g5, 256, 0, stream>>>(
        up4, conv1, cw[4], cb[4], graw[4], cs[4], kp, m5, nullptr);

    // ---- final 1x1
    final1x1<<<CDIV(BATCH * 196), 256, 0, stream>>>(m5, wlast, blast, out);
    #undef CDIV
}

// Round 6
// 871.254 us; speedup vs baseline: 2.8481x; 1.5151x over previous
//
#include <hip/hip_runtime.h>
#include <hip/hip_bf16.h>
#include <math.h>

// ---------------------------------------------------------------------------
// Generalised gated MoE U-net, B=2048, E=4, W=10, fp32 throughout.
// Round 6: KILL same-address atomics (gate colsum 2048-way contention ->
//   dedicated 1-block gate_reduce kernel). Fuse final 1x1 conv into conv5
//   epilogue via distinct-address atomics (+bias/5 per cout-group partial).
//   Conv structure unchanged from R5 (4-row strip, CG=2, ping-pong prefetch,
//   fused pool, XCD swizzle, inline gate finalize).
// ---------------------------------------------------------------------------

constexpr int BATCH = 2048;

// ---------------- workspace layout (in floats) ----------------
constexpr size_t PADF    = 1024;                       // 4KB guard pads
constexpr size_t F_CONV1 = (size_t)BATCH * 10 * 784;
constexpr size_t F_XPAD  = (size_t)BATCH * 784;
constexpr size_t F_P1    = (size_t)BATCH * 10 * 196;
constexpr size_t F_CONV2 = F_P1;
constexpr size_t F_P2    = (size_t)BATCH * 10 * 49;
constexpr size_t F_CONV3 = (size_t)BATCH * 20 * 49;
constexpr size_t F_UP3   = (size_t)BATCH * 20 * 196;
constexpr size_t F_M4    = F_P1;
constexpr size_t F_UP4   = F_CONV1;

constexpr size_t O_CONV1 = PADF;
constexpr size_t O_Z2    = O_CONV1 + F_CONV1 + PADF;
constexpr size_t O_XPAD  = O_Z2;
constexpr size_t O_P1    = O_XPAD + F_XPAD + PADF;
constexpr size_t O_CONV2 = O_P1 + F_P1 + PADF;
constexpr size_t O_P2    = O_CONV2 + F_CONV2 + PADF;
constexpr size_t O_CONV3 = O_P2 + F_P2 + PADF;
constexpr size_t O_UP3   = O_CONV3 + F_CONV3 + PADF;
constexpr size_t O_M4    = O_UP3 + F_UP3 + PADF;
constexpr size_t O_UP4   = O_Z2;                        // overlays dead xpad..up3
constexpr size_t O_GRAW  = O_M4 + F_M4 + PADF;          // after m4 zone
constexpr size_t O_CS    = O_GRAW + 5 * (size_t)BATCH * 4;  // 5 x 64
constexpr size_t WS_FLOATS = O_CS + 5 * 64 + PADF;

__device__ __forceinline__ float softplusf(float z) {
    return fmaxf(z, 0.0f) + log1pf(expf(-fabsf(z)));
}

__device__ __forceinline__ float4 ld4(const float* p) {
    return *(const float4*)p;
}

constexpr int cdivc(int a, int b) { return (a + b - 1) / b; }
constexpr int pb4(int H, int W) {          // 4-row strips; exact mult of 256
    return cdivc(BATCH * ((H + 3) / 4) * W, 256);
}

// ---------------- gate: block per sample, float4 path (no atomics) ---------
template <int C1HW, int C2HW>
__global__ __launch_bounds__(256) void gate_block_v4(
    const float* __restrict__ x1, const float* __restrict__ x2,
    const float* __restrict__ gw, const float* __restrict__ gb,
    const float* __restrict__ nw, const float* __restrict__ nb,
    const float* __restrict__ eps,
    float* __restrict__ graw)
{
    constexpr int DV = (C1HW + C2HW) / 4;
    const int b   = blockIdx.x;
    const int tid = threadIdx.x;

    float ga0 = 0.f, ga1 = 0.f, ga2 = 0.f, ga3 = 0.f;
    float na0 = 0.f, na1 = 0.f, na2 = 0.f, na3 = 0.f;

    for (int g = tid; g < DV; g += 256) {
        const int d = g * 4;
        float4 xv;
        if constexpr (C2HW > 0) {
            xv = (d < C1HW) ? ld4(x1 + (size_t)b * C1HW + d)
                            : ld4(x2 + (size_t)b * C2HW + (d - C1HW));
        } else {
            xv = ld4(x1 + (size_t)b * C1HW + d);
        }
        const float xs[4] = {xv.x, xv.y, xv.z, xv.w};
        #pragma unroll
        for (int j = 0; j < 4; ++j) {
            const float val = xs[j];
            const float4 gv = ((const float4*)gw)[d + j];
            const float4 nv = ((const float4*)nw)[d + j];
            ga0 = fmaf(val, gv.x, ga0); ga1 = fmaf(val, gv.y, ga1);
            ga2 = fmaf(val, gv.z, ga2); ga3 = fmaf(val, gv.w, ga3);
            na0 = fmaf(val, nv.x, na0); na1 = fmaf(val, nv.y, na1);
            na2 = fmaf(val, nv.z, na2); na3 = fmaf(val, nv.w, na3);
        }
    }
    #pragma unroll
    for (int m = 32; m >= 1; m >>= 1) {
        ga0 += __shfl_xor(ga0, m, 64); ga1 += __shfl_xor(ga1, m, 64);
        ga2 += __shfl_xor(ga2, m, 64); ga3 += __shfl_xor(ga3, m, 64);
        na0 += __shfl_xor(na0, m, 64); na1 += __shfl_xor(na1, m, 64);
        na2 += __shfl_xor(na2, m, 64); na3 += __shfl_xor(na3, m, 64);
    }
    __shared__ float red[4][8];
    const int wave = tid >> 6, lane = tid & 63;
    if (lane == 0) {
        red[wave][0] = ga0; red[wave][1] = ga1; red[wave][2] = ga2; red[wave][3] = ga3;
        red[wave][4] = na0; red[wave][5] = na1; red[wave][6] = na2; red[wave][7] = na3;
    }
    __syncthreads();
    if (tid == 0) {
        float G[8];
        #pragma unroll
        for (int i = 0; i < 8; ++i)
            G[i] = red[0][i] + red[1][i] + red[2][i] + red[3][i];
        #pragma unroll
        for (int e = 0; e < 4; ++e) {
            graw[b * 4 + e] = G[e] + gb[e] + eps[e] * softplusf(G[4 + e] + nb[e]);
        }
    }
}

// scalar variant (D=490)
template <int D>
__global__ __launch_bounds__(256) void gate_block_s(
    const float* __restrict__ x1,
    const float* __restrict__ gw, const float* __restrict__ gb,
    const float* __restrict__ nw, const float* __restrict__ nb,
    const float* __restrict__ eps,
    float* __restrict__ graw)
{
    const int b   = blockIdx.x;
    const int tid = threadIdx.x;

    float ga0 = 0.f, ga1 = 0.f, ga2 = 0.f, ga3 = 0.f;
    float na0 = 0.f, na1 = 0.f, na2 = 0.f, na3 = 0.f;

    for (int d = tid; d < D; d += 256) {
        const float val = x1[(size_t)b * D + d];
        const float4 gv = ((const float4*)gw)[d];
        const float4 nv = ((const float4*)nw)[d];
        ga0 = fmaf(val, gv.x, ga0); ga1 = fmaf(val, gv.y, ga1);
        ga2 = fmaf(val, gv.z, ga2); ga3 = fmaf(val, gv.w, ga3);
        na0 = fmaf(val, nv.x, na0); na1 = fmaf(val, nv.y, na1);
        na2 = fmaf(val, nv.z, na2); na3 = fmaf(val, nv.w, na3);
    }
    #pragma unroll
    for (int m = 32; m >= 1; m >>= 1) {
        ga0 += __shfl_xor(ga0, m, 64); ga1 += __shfl_xor(ga1, m, 64);
        ga2 += __shfl_xor(ga2, m, 64); ga3 += __shfl_xor(ga3, m, 64);
        na0 += __shfl_xor(na0, m, 64); na1 += __shfl_xor(na1, m, 64);
        na2 += __shfl_xor(na2, m, 64); na3 += __shfl_xor(na3, m, 64);
    }
    __shared__ float red[4][8];
    const int wave = tid >> 6, lane = tid & 63;
    if (lane == 0) {
        red[wave][0] = ga0; red[wave][1] = ga1; red[wave][2] = ga2; red[wave][3] = ga3;
        red[wave][4] = na0; red[wave][5] = na1; red[wave][6] = na2; red[wave][7] = na3;
    }
    __syncthreads();
    if (tid == 0) {
        float G[8];
        #pragma unroll
        for (int i = 0; i < 8; ++i)
            G[i] = red[0][i] + red[1][i] + red[2][i] + red[3][i];
        #pragma unroll
        for (int e = 0; e < 4; ++e) {
            graw[b * 4 + e] = G[e] + gb[e] + eps[e] * softplusf(G[4 + e] + nb[e]);
        }
    }
}

// ---------------- gate reduce: colsum over batch (1 block, no atomics) -----
__global__ __launch_bounds__(256) void gate_reduce(
    const float* __restrict__ graw, float* __restrict__ cs)
{
    const int tid = threadIdx.x;
    float a0 = 0.f, a1 = 0.f, a2 = 0.f, a3 = 0.f;
    for (int b = tid; b < BATCH; b += 256) {
        const float4 v = ld4(graw + b * 4);
        a0 += v.x; a1 += v.y; a2 += v.z; a3 += v.w;
    }
    #pragma unroll
    for (int m = 32; m >= 1; m >>= 1) {
        a0 += __shfl_xor(a0, m, 64); a1 += __shfl_xor(a1, m, 64);
        a2 += __shfl_xor(a2, m, 64); a3 += __shfl_xor(a3, m, 64);
    }
    __shared__ float red[4][4];
    const int wave = tid >> 6, lane = tid & 63;
    if (lane == 0) {
        red[wave][0] = a0; red[wave][1] = a1; red[wave][2] = a2; red[wave][3] = a3;
    }
    __syncthreads();
    if (tid < 4) {
        cs[tid] = red[0][tid] + red[1][tid] + red[2][tid] + red[3][tid];
    }
}

// ---------------- MoE conv 3x3 SAME + relu + gated sum ---------------------
// Thread = (b, w, 4-row strip) x CG=2 couts x 4 experts. Ping-pong tap
// prefetch over ci. Gate finalize (top-k + masked softmax) inlined.
// POOL=1: fused 2x2 maxpool via shfl_xor(1).
// FINAL=1: fused 1x1 conv -> atomicAdd partials (+bias/NCG) into out.
template <int CIN1, int CIN2, int COUT, int H, int W, int POOL, int FINAL>
__global__ __launch_bounds__(256) void moe_conv4(
    const float* __restrict__ x1, const float* __restrict__ x2,
    const float* __restrict__ cw, const float* __restrict__ cb,
    const float* __restrict__ graw, const float* __restrict__ colsum,
    const int* __restrict__ kp,
    float* __restrict__ out, float* __restrict__ pout,
    const float* __restrict__ wl, const float* __restrict__ bl)
{
    constexpr int CIN = CIN1 + CIN2;
    constexpr int CG  = 2;
    constexpr int NCG = COUT / CG;
    constexpr int HG  = (H + 3) / 4;
    constexpr int TOTAL = BATCH * HG * W;

    __shared__ __align__(16) float wlds[CIN * 72];   // [ci][k][j*4+e]

    const unsigned bid = blockIdx.x;
    const unsigned xcd = bid & 7u;
    const unsigned sub = bid >> 3;
    const unsigned cg  = sub % NCG;
    const unsigned tl  = sub / NCG;
    const unsigned tile = tl * 8u + xcd;
    const int c0 = (int)cg * CG;

    for (int idx = threadIdx.x; idx < CIN * 72; idx += 256) {
        const int ci = idx / 72;
        const int r  = idx % 72;
        const int k  = r / 8;
        const int je = r % 8;
        wlds[idx] = cw[((size_t)((je & 3) * COUT + c0 + (je >> 2)) * CIN + ci) * 9 + k];
    }
    __syncthreads();

    const int t = (int)tile * 256 + (int)threadIdx.x;
    if (t >= TOTAL) return;                    // TOTAL % 256 == 0: never taken
    const int b  = t / (HG * W);
    const int r  = t - b * (HG * W);
    const int hg = r / W;
    const int w  = r - hg * W;
    const int h0 = hg * 4;

    // ---- inline gate finalize: top-k (by colsum) + masked softmax ----
    float gt[4];
    {
        int k = kp[0];
        k = (k < 1) ? 1 : (k > 4 ? 4 : k);
        float cs[4], gr[4];
        bool sel[4] = {false, false, false, false};
        #pragma unroll
        for (int e = 0; e < 4; ++e) { cs[e] = colsum[e]; gr[e] = graw[b * 4 + e]; }
        for (int it = 0; it < k; ++it) {
            int bi = 0; float bv = -INFINITY;
            #pragma unroll
            for (int e = 0; e < 4; ++e)
                if (!sel[e] && cs[e] > bv) { bv = cs[e]; bi = e; }
            sel[bi] = true;
        }
        float g[4];
        #pragma unroll
        for (int e = 0; e < 4; ++e) g[e] = sel[e] ? gr[e] : 0.0f;
        const float mx = fmaxf(fmaxf(g[0], g[1]), fmaxf(g[2], g[3]));
        const float e0 = expf(g[0] - mx), e1 = expf(g[1] - mx);
        const float e2 = expf(g[2] - mx), e3 = expf(g[3] - mx);
        const float inv = 1.0f / (e0 + e1 + e2 + e3);
        gt[0] = e0 * inv; gt[1] = e1 * inv; gt[2] = e2 * inv; gt[3] = e3 * inv;
    }

    // combined tap masks (6 rows x 3 cols)
    float m[6][3];
    #pragma unroll
    for (int rr = 0; rr < 6; ++rr) {
        const int y = h0 - 1 + rr;
        const float my = (y >= 0 && y < H) ? 1.0f : 0.0f;
        #pragma unroll
        for (int dc = 0; dc < 3; ++dc) {
            const int xx = w - 1 + dc;
            m[rr][dc] = ((xx >= 0 && xx < W) ? 1.0f : 0.0f) * my;
        }
    }
    const int base = (h0 - 1) * W + (w - 1);   // may be negative; pads guard

    float acc[4][CG][4];
    #pragma unroll
    for (int j = 0; j < CG; ++j) {
        #pragma unroll
        for (int e = 0; e < 4; ++e) {
            const float bv = cb[e * COUT + c0 + j];
            #pragma unroll
            for (int rr = 0; rr < 4; ++rr) acc[rr][j][e] = bv;
        }
    }

    const float* xb1 = x1 + (size_t)b * CIN1 * (H * W);
    const float* xb2 = (CIN2 > 0) ? (x2 + (size_t)b * CIN2 * (H * W)) : nullptr;

    auto xplane = [&](int ci) -> const float* {
        if constexpr (CIN2 > 0)
            return (ci < CIN1) ? (xb1 + ci * (H * W)) : (xb2 + (ci - CIN1) * (H * W));
        else
            return xb1 + ci * (H * W);
    };
    auto load_taps = [&](int ci, float v[6][3]) {
        const float* xp = xplane(ci);
        #pragma unroll
        for (int rr = 0; rr < 6; ++rr)
            #pragma unroll
            for (int dc = 0; dc < 3; ++dc)
                v[rr][dc] = xp[base + rr * W + dc];
    };
    auto fma_taps = [&](int ci, const float v[6][3]) {
        float mv[6][3];
        #pragma unroll
        for (int rr = 0; rr < 6; ++rr)
            #pragma unroll
            for (int dc = 0; dc < 3; ++dc)
                mv[rr][dc] = v[rr][dc] * m[rr][dc];
        const float4* wp = (const float4*)&wlds[ci * 72];
        #pragma unroll
        for (int k = 0; k < 9; ++k) {
            const float4 wA = wp[k * 2];
            const float4 wB = wp[k * 2 + 1];
            const int kh = k / 3, kw = k % 3;
            #pragma unroll
            for (int rr = 0; rr < 4; ++rr) {
                const float tap = mv[rr + kh][kw];
                acc[rr][0][0] = fmaf(tap, wA.x, acc[rr][0][0]);
                acc[rr][0][1] = fmaf(tap, wA.y, acc[rr][0][1]);
                acc[rr][0][2] = fmaf(tap, wA.z, acc[rr][0][2]);
                acc[rr][0][3] = fmaf(tap, wA.w, acc[rr][0][3]);
                acc[rr][1][0] = fmaf(tap, wB.x, acc[rr][1][0]);
                acc[rr][1][1] = fmaf(tap, wB.y, acc[rr][1][1]);
                acc[rr][1][2] = fmaf(tap, wB.z, acc[rr][1][2]);
                acc[rr][1][3] = fmaf(tap, wB.w, acc[rr][1][3]);
            }
        }
    };

    // software pipeline: ping-pong prefetch one ci ahead
    float vA[6][3], vB[6][3];
    load_taps(0, vA);
    #pragma unroll 1
    for (int ci = 0; ci + 2 <= CIN; ci += 2) {
        load_taps(ci + 1, vB);
        fma_taps(ci, vA);
        if (ci + 2 < CIN) load_taps(ci + 2, vA);
        fma_taps(ci + 1, vB);
    }
    if constexpr (CIN & 1) {
        fma_taps(CIN - 1, vA);
    }

    // ---- epilogue: relu + gated sum ----
    float s[4][CG];
    #pragma unroll
    for (int rr = 0; rr < 4; ++rr)
        #pragma unroll
        for (int j = 0; j < CG; ++j)
            s[rr][j] = gt[0] * fmaxf(acc[rr][j][0], 0.f)
                     + gt[1] * fmaxf(acc[rr][j][1], 0.f)
                     + gt[2] * fmaxf(acc[rr][j][2], 0.f)
                     + gt[3] * fmaxf(acc[rr][j][3], 0.f);

    if constexpr (FINAL) {
        // fused 1x1: atomic partial (+ bias/NCG) into out [B,1,H,W]
        const float w0 = wl[c0], w1 = wl[c0 + 1];
        const float bshare = bl[0] * (1.0f / (float)NCG);
        float* op = out + (size_t)b * (H * W) + h0 * W + w;
        #pragma unroll
        for (int rr = 0; rr < 4; ++rr) {
            if (h0 + rr < H)
                atomicAdd(&op[rr * W], s[rr][0] * w0 + s[rr][1] * w1 + bshare);
        }
    } else {
        #pragma unroll
        for (int j = 0; j < CG; ++j) {
            float* op = out + ((size_t)b * COUT + c0 + j) * (H * W) + h0 * W + w;
            #pragma unroll
            for (int rr = 0; rr < 4; ++rr)
                if (h0 + rr < H) op[rr * W] = s[rr][j];
        }
    }

    if constexpr (POOL) {
        constexpr int H2 = H / 2, W2 = W / 2;
        #pragma unroll
        for (int j = 0; j < CG; ++j) {
            float cm0 = fmaxf(s[0][j], s[1][j]);
            float cm1 = fmaxf(s[2][j], s[3][j]);
            const float o0 = fmaxf(cm0, __shfl_xor(cm0, 1, 64));
            const float o1 = fmaxf(cm1, __shfl_xor(cm1, 1, 64));
            if ((w & 1) == 0) {
                const int pr0 = h0 >> 1;
                float* pp = pout + ((size_t)b * COUT + c0 + j) * (H2 * W2) + (w >> 1);
                if (pr0     < H2) pp[pr0 * W2]       = o0;
                if (pr0 + 1 < H2) pp[(pr0 + 1) * W2] = o1;
            }
        }
    }
}

// ---------------- bilinear x2 upsample, align_corners=True ----------------
template <int N>
__global__ __launch_bounds__(256) void upsample2(
    const float* __restrict__ in, float* __restrict__ out, int BC)
{
    constexpr int M = 2 * N;
    const int idx = blockIdx.x * 256 + threadIdx.x;
    const int total = BC * M * M;
    if (idx >= total) return;
    const int x = idx % M;
    int tmp = idx / M;
    const int y = tmp % M;
    const int bc = tmp / M;
    const float scale = (float)((double)(N - 1) / (double)(M - 1));
    const float cy = (float)y * scale;
    const float cx = (float)x * scale;
    const int iy0 = (int)floorf(cy);
    const int ix0 = (int)floorf(cx);
    const int iy1 = min(iy0 + 1, N - 1);
    const int ix1 = min(ix0 + 1, N - 1);
    const float wy = cy - (float)iy0;
    const float wx = cx - (float)ix0;
    const float* p = in + (size_t)bc * N * N;
    const float v00 = p[iy0 * N + ix0], v01 = p[iy0 * N + ix1];
    const float v10 = p[iy1 * N + ix0], v11 = p[iy1 * N + ix1];
    const float a0 = v00 * (1.0f - wy) + v10 * wy;
    const float a1 = v01 * (1.0f - wy) + v11 * wy;
    out[idx] = a0 * (1.0f - wx) + a1 * wx;
}

// ---------------------------------------------------------------------------
extern "C" void kernel_launch(void* const* d_in, const int* in_sizes, int n_in,
                              void* d_out, int out_size, void* d_ws, size_t ws_size,
                              hipStream_t stream)
{
    const float* x = (const float*)d_in[0];
    const float* cw[5]; const float* cb[5]; const float* gw[5]; const float* gb[5];
    const float* nw[5]; const float* nb[5]; const float* epsv[5];
    for (int l = 0; l < 5; ++l) {
        cw[l]   = (const float*)d_in[1 + 7 * l + 0];
        cb[l]   = (const float*)d_in[1 + 7 * l + 1];
        gw[l]   = (const float*)d_in[1 + 7 * l + 2];
        gb[l]   = (const float*)d_in[1 + 7 * l + 3];
        nw[l]   = (const float*)d_in[1 + 7 * l + 4];
        nb[l]   = (const float*)d_in[1 + 7 * l + 5];
        epsv[l] = (const float*)d_in[1 + 7 * l + 6];
    }
    const float* wlast = (const float*)d_in[36];
    const float* blast = (const float*)d_in[37];
    const int*   kp    = (const int*)d_in[38];
    float* out = (float*)d_out;
    float* ws  = (float*)d_ws;

    float* conv1 = ws + O_CONV1;
    float* xpad  = ws + O_XPAD;
    float* p1    = ws + O_P1;
    float* conv2 = ws + O_CONV2;
    float* p2    = ws + O_P2;
    float* conv3 = ws + O_CONV3;
    float* up3   = ws + O_UP3;
    float* m4    = ws + O_M4;
    float* up4   = ws + O_UP4;
    float* graw[5]; float* cs[5];
    for (int l = 0; l < 5; ++l) {
        graw[l] = ws + O_GRAW + (size_t)l * BATCH * 4;
        cs[l]   = ws + O_CS + (size_t)l * 64;
    }

    // out is re-poisoned before every launch; zero it for the atomic epilogue
    hipMemsetAsync(out, 0, (size_t)out_size * sizeof(float), stream);
    hipMemcpyAsync(xpad, x, (size_t)BATCH * 784 * sizeof(float),
                   hipMemcpyDeviceToDevice, stream);

    #define CDIV(a) (((a) + 255) / 256)
    const int g1 = pb4(28, 28) * 5;   // 1568 * 5
    const int g2 = pb4(14, 14) * 5;   //  448 * 5
    const int g3 = pb4(7, 7)   * 10;  //  112 * 10
    const int g4 = pb4(14, 14) * 5;
    const int g5 = pb4(28, 28) * 5;

    // ---- layer 1: x [B,1,28,28] -> conv1 + p1 (fused pool)
    gate_block_v4<784, 0><<<BATCH, 256, 0, stream>>>(
        x, nullptr, gw[0], gb[0], nw[0], nb[0], epsv[0], graw[0]);
    gate_reduce<<<1, 256, 0, stream>>>(graw[0], cs[0]);
    moe_conv4<1, 0, 10, 28, 28, 1, 0><<<g1, 256, 0, stream>>>(
        xpad, nullptr, cw[0], cb[0], graw[0], cs[0], kp, conv1, p1,
        nullptr, nullptr);

    // ---- layer 2: p1 -> conv2 + p2 (fused pool)
    gate_block_v4<1960, 0><<<BATCH, 256, 0, stream>>>(
        p1, nullptr, gw[1], gb[1], nw[1], nb[1], epsv[1], graw[1]);
    gate_reduce<<<1, 256, 0, stream>>>(graw[1], cs[1]);
    moe_conv4<10, 0, 10, 14, 14, 1, 0><<<g2, 256, 0, stream>>>(
        p1, nullptr, cw[1], cb[1], graw[1], cs[1], kp, conv2, p2,
        nullptr, nullptr);

    // ---- layer 3: p2 -> conv3 -> up3
    gate_block_s<490><<<BATCH, 256, 0, stream>>>(
        p2, gw[2], gb[2], nw[2], nb[2], epsv[2], graw[2]);
    gate_reduce<<<1, 256, 0, stream>>>(graw[2], cs[2]);
    moe_conv4<10, 0, 20, 7, 7, 0, 0><<<g3, 256, 0, stream>>>(
        p2, nullptr, cw[2], cb[2], graw[2], cs[2], kp, conv3, nullptr,
        nullptr, nullptr);
    upsample2<7><<<CDIV(BATCH * 20 * 196), 256, 0, stream>>>(conv3, up3, BATCH * 20);

    // ---- layer 4: [up3 | conv2] -> m4 -> up4
    gate_block_v4<3920, 1960><<<BATCH, 256, 0, stream>>>(
        up3, conv2, gw[3], gb[3], nw[3], nb[3], epsv[3], graw[3]);
    gate_reduce<<<1, 256, 0, stream>>>(graw[3], cs[3]);
    moe_conv4<20, 10, 10, 14, 14, 0, 0><<<g4, 256, 0, stream>>>(
        up3, conv2, cw[3], cb[3], graw[3], cs[3], kp, m4, nullptr,
        nullptr, nullptr);
    upsample2<14><<<CDIV(BATCH * 10 * 784), 256, 0, stream>>>(m4, up4, BATCH * 10);

    // ---- layer 5: [up4 | conv1] -> fused (conv + gate + final 1x1) -> out
    gate_block_v4<7840, 7840><<<BATCH, 256, 0, stream>>>(
        up4, conv1, gw[4], gb[4], nw[4], nb[4], epsv[4], graw[4]);
    gate_reduce<<<1, 256, 0, stream>>>(graw[4], cs[4]);
    moe_conv4<10, 10, 10, 28, 28, 0, 1><<<g5, 256, 0, stream>>>(
        up4, conv1, cw[4], cb[4], graw[4], cs[4], kp, out, nullptr,
        wlast, blast);
    #undef CDIV
}